// Round 1
// baseline (1593.960 us; speedup 1.0000x reference)
//
#include <hip/hip_runtime.h>
#include <cstddef>

#define B_DIM   2
#define S_LEN   2048
#define EMB     1024
#define NH      16
#define HD      64
#define QKV_N   3072
#define MASKED_BIAS -10000.0f

// ---------------------------------------------------------------------------
// Generic SGEMM: C[M,N] = X[M,K] @ W[K,N] + bias[N]
// BM=128 BN=128 BK=8, 8x8 micro-tile, 256 threads. Requires M%128==N%128==0,
// K%8==0. Software-prefetch of the next global tile hides load latency.
// ---------------------------------------------------------------------------
__global__ __launch_bounds__(256)
void sgemm_bias(const float* __restrict__ X, const float* __restrict__ W,
                const float* __restrict__ bias, float* __restrict__ C,
                int M, int N, int K)
{
    constexpr int BM = 128, BN = 128, BK = 8;
    __shared__ float As[BK][BM];   // A tile, transposed ([k][m])
    __shared__ float Bs[BK][BN];   // B tile, natural ([k][n])

    const int tid = threadIdx.x;
    const int bx = blockIdx.x, by = blockIdx.y;
    const int tx = tid & 15, ty = tid >> 4;

    // global-load mappings (one float4 each per tile)
    const int a_row = tid >> 1;            // 0..127
    const int a_col = (tid & 1) << 2;      // 0 or 4
    const int b_row = tid >> 5;            // 0..7
    const int b_col = (tid & 31) << 2;     // 0..124

    float acc[8][8];
#pragma unroll
    for (int i = 0; i < 8; ++i)
#pragma unroll
        for (int j = 0; j < 8; ++j) acc[i][j] = 0.0f;

    const float* Xp = X + (size_t)(by * BM + a_row) * K + a_col;
    const float* Wp = W + (size_t)b_row * N + (size_t)bx * BN + b_col;

    float4 av = *(const float4*)(Xp);
    float4 bv = *(const float4*)(Wp);

    for (int k0 = 0; k0 < K; k0 += BK) {
        As[a_col + 0][a_row] = av.x;
        As[a_col + 1][a_row] = av.y;
        As[a_col + 2][a_row] = av.z;
        As[a_col + 3][a_row] = av.w;
        *(float4*)&Bs[b_row][b_col] = bv;
        __syncthreads();

        // prefetch next tile while computing this one
        if (k0 + BK < K) {
            av = *(const float4*)(Xp + k0 + BK);
            bv = *(const float4*)(Wp + (size_t)(k0 + BK) * N);
        }

#pragma unroll
        for (int kk = 0; kk < BK; ++kk) {
            float4 a0 = *(const float4*)&As[kk][ty * 8];
            float4 a1 = *(const float4*)&As[kk][ty * 8 + 4];
            float4 b0 = *(const float4*)&Bs[kk][tx * 8];
            float4 b1 = *(const float4*)&Bs[kk][tx * 8 + 4];
            float a[8] = {a0.x, a0.y, a0.z, a0.w, a1.x, a1.y, a1.z, a1.w};
            float b[8] = {b0.x, b0.y, b0.z, b0.w, b1.x, b1.y, b1.z, b1.w};
#pragma unroll
            for (int i = 0; i < 8; ++i)
#pragma unroll
                for (int j = 0; j < 8; ++j)
                    acc[i][j] = fmaf(a[i], b[j], acc[i][j]);
        }
        __syncthreads();
    }

    const int c0 = bx * BN + tx * 8;
    const float4 bias0 = *(const float4*)(bias + c0);
    const float4 bias1 = *(const float4*)(bias + c0 + 4);
#pragma unroll
    for (int i = 0; i < 8; ++i) {
        const size_t row = (size_t)(by * BM + ty * 8 + i);
        float4 o0, o1;
        o0.x = acc[i][0] + bias0.x;  o0.y = acc[i][1] + bias0.y;
        o0.z = acc[i][2] + bias0.z;  o0.w = acc[i][3] + bias0.w;
        o1.x = acc[i][4] + bias1.x;  o1.y = acc[i][5] + bias1.y;
        o1.z = acc[i][6] + bias1.z;  o1.w = acc[i][7] + bias1.w;
        *(float4*)(C + row * N + c0)     = o0;
        *(float4*)(C + row * N + c0 + 4) = o1;
    }
}

// ---------------------------------------------------------------------------
// Flash attention (fp32). Grid: (S/64, B*H). Block: 256 threads.
// Each block: one (b, h) and 64 query rows. Iterates kt = 0..qt (causal),
// online softmax, P@V accumulated in registers.
// qkv layout: [B*S, 3072] row-major; q at col 0, k at 1024, v at 2048,
// with head h occupying cols h*64 .. h*64+63 within each third.
// ---------------------------------------------------------------------------
__global__ __launch_bounds__(256)
void attn_fa(const float* __restrict__ qkv, float* __restrict__ out)
{
    const int qt = blockIdx.x;          // 0..31
    const int bh = blockIdx.y;          // 0..31
    const int b  = bh >> 4, h = bh & 15;
    const int tid = threadIdx.x;
    const int tx = tid & 15, ty = tid >> 4;

    __shared__ float Qt[HD][68];   // Q^T  [d][r]   (68: 16B-aligned rows, bank shift)
    __shared__ float Kt[HD][68];   // K^T  [d][c]
    __shared__ float Vs[64][68];   // V    [c][d]
    __shared__ float Ps[64][68];   // P    [r][c]

    const float scale = 1.0f / 16.0f;   // 1/sqrt(64)/LAYER_IDX
    const size_t row0 = (size_t)b * S_LEN;

    // ---- load Q tile (transposed into LDS) ----
#pragma unroll
    for (int rep = 0; rep < 4; ++rep) {
        int e = rep * 256 + tid;          // 0..1023
        int r = e >> 4;                   // 0..63
        int d = (e & 15) << 2;            // 0..60
        float4 q4 = *(const float4*)(qkv + (row0 + qt * 64 + r) * QKV_N + h * HD + d);
        Qt[d + 0][r] = q4.x;
        Qt[d + 1][r] = q4.y;
        Qt[d + 2][r] = q4.z;
        Qt[d + 3][r] = q4.w;
    }

    float m_i[4], l_i[4], o[4][4];
#pragma unroll
    for (int i = 0; i < 4; ++i) {
        m_i[i] = -1e30f; l_i[i] = 0.0f;
#pragma unroll
        for (int j = 0; j < 4; ++j) o[i][j] = 0.0f;
    }

    for (int kt = 0; kt <= qt; ++kt) {
        __syncthreads();   // previous PV done with Vs/Ps; compute done with Kt
        // ---- load K (transposed) and V (natural) tiles ----
#pragma unroll
        for (int rep = 0; rep < 4; ++rep) {
            int e = rep * 256 + tid;
            int r = e >> 4;
            int d = (e & 15) << 2;
            const float* src = qkv + (row0 + kt * 64 + r) * QKV_N + h * HD;
            float4 k4 = *(const float4*)(src + EMB + d);
            Kt[d + 0][r] = k4.x;
            Kt[d + 1][r] = k4.y;
            Kt[d + 2][r] = k4.z;
            Kt[d + 3][r] = k4.w;
            float4 v4 = *(const float4*)(src + 2 * EMB + d);
            *(float4*)&Vs[r][d] = v4;
        }
        __syncthreads();

        // ---- S = Q K^T (64x64 tile, 4x4 per thread) ----
        float s[4][4];
#pragma unroll
        for (int i = 0; i < 4; ++i)
#pragma unroll
            for (int j = 0; j < 4; ++j) s[i][j] = 0.0f;

#pragma unroll
        for (int kk = 0; kk < HD; ++kk) {
            float4 qv = *(const float4*)&Qt[kk][ty * 4];
            float4 kv = *(const float4*)&Kt[kk][tx * 4];
            float qa[4] = {qv.x, qv.y, qv.z, qv.w};
            float ka[4] = {kv.x, kv.y, kv.z, kv.w};
#pragma unroll
            for (int i = 0; i < 4; ++i)
#pragma unroll
                for (int j = 0; j < 4; ++j)
                    s[i][j] = fmaf(qa[i], ka[j], s[i][j]);
        }

        // ---- scale + causal mask (diagonal tile only) ----
        if (kt == qt) {
#pragma unroll
            for (int i = 0; i < 4; ++i)
#pragma unroll
                for (int j = 0; j < 4; ++j)
                    s[i][j] = (tx * 4 + j > ty * 4 + i) ? MASKED_BIAS
                                                        : s[i][j] * scale;
        } else {
#pragma unroll
            for (int i = 0; i < 4; ++i)
#pragma unroll
                for (int j = 0; j < 4; ++j) s[i][j] *= scale;
        }

        // ---- online softmax (row reductions across the 16 tx lanes) ----
#pragma unroll
        for (int i = 0; i < 4; ++i) {
            float rm = fmaxf(fmaxf(s[i][0], s[i][1]), fmaxf(s[i][2], s[i][3]));
#pragma unroll
            for (int off = 1; off < 16; off <<= 1)
                rm = fmaxf(rm, __shfl_xor(rm, off, 64));
            float mnew  = fmaxf(m_i[i], rm);
            float alpha = __expf(m_i[i] - mnew);
            float rs = 0.0f;
#pragma unroll
            for (int j = 0; j < 4; ++j) {
                s[i][j] = __expf(s[i][j] - mnew);
                rs += s[i][j];
            }
#pragma unroll
            for (int off = 1; off < 16; off <<= 1)
                rs += __shfl_xor(rs, off, 64);
            l_i[i] = l_i[i] * alpha + rs;
            m_i[i] = mnew;
#pragma unroll
            for (int j = 0; j < 4; ++j) o[i][j] *= alpha;
        }

        // ---- stage P in LDS, then O += P @ V ----
#pragma unroll
        for (int i = 0; i < 4; ++i)
            *(float4*)&Ps[ty * 4 + i][tx * 4] =
                make_float4(s[i][0], s[i][1], s[i][2], s[i][3]);
        __syncthreads();

#pragma unroll 8
        for (int c = 0; c < 64; ++c) {
            float4 vv = *(const float4*)&Vs[c][tx * 4];
            float va[4] = {vv.x, vv.y, vv.z, vv.w};
#pragma unroll
            for (int i = 0; i < 4; ++i) {
                float p = Ps[ty * 4 + i][c];
#pragma unroll
                for (int j = 0; j < 4; ++j)
                    o[i][j] = fmaf(p, va[j], o[i][j]);
            }
        }
    }

    // ---- normalize and write [B,S,E] ----
#pragma unroll
    for (int i = 0; i < 4; ++i) {
        float inv = 1.0f / l_i[i];
        float4 ov = make_float4(o[i][0] * inv, o[i][1] * inv,
                                o[i][2] * inv, o[i][3] * inv);
        *(float4*)(out + (row0 + qt * 64 + ty * 4 + i) * EMB + h * HD + tx * 4) = ov;
    }
}

// ---------------------------------------------------------------------------
extern "C" void kernel_launch(void* const* d_in, const int* in_sizes, int n_in,
                              void* d_out, int out_size, void* d_ws, size_t ws_size,
                              hipStream_t stream)
{
    const float* hidden = (const float*)d_in[0];   // [B,S,E]
    const float* w_attn = (const float*)d_in[1];   // [E,3E]
    const float* b_attn = (const float*)d_in[2];   // [3E]
    const float* w_proj = (const float*)d_in[3];   // [E,E]
    const float* b_proj = (const float*)d_in[4];   // [E]
    float* out = (float*)d_out;                    // [B,S,E]

    float* qkv  = (float*)d_ws;                          // [4096, 3072]
    float* attn = qkv + (size_t)B_DIM * S_LEN * QKV_N;   // [4096, 1024]

    const int M = B_DIM * S_LEN;   // 4096

    dim3 blk(256);
    // 1) QKV = hidden @ w_attn + b_attn
    sgemm_bias<<<dim3(QKV_N / 128, M / 128), blk, 0, stream>>>(
        hidden, w_attn, b_attn, qkv, M, QKV_N, EMB);
    // 2) flash attention
    attn_fa<<<dim3(S_LEN / 64, B_DIM * NH), blk, 0, stream>>>(qkv, attn);
    // 3) out = attn @ w_proj + b_proj
    sgemm_bias<<<dim3(EMB / 128, M / 128), blk, 0, stream>>>(
        attn, w_proj, b_proj, out, M, EMB, EMB);
}

// Round 2
// 275.864 us; speedup vs baseline: 5.7781x; 5.7781x over previous
//
#include <hip/hip_runtime.h>
#include <cstddef>

#define B_DIM   2
#define S_LEN   2048
#define EMB     1024
#define NH      16
#define HD      64
#define QKV_N   3072
#define MROWS   (B_DIM * S_LEN)
#define MASKED_BIAS -10000.0f

using half8  = __attribute__((ext_vector_type(8))) _Float16;
using half4v = __attribute__((ext_vector_type(4))) _Float16;
using f32x4  = __attribute__((ext_vector_type(4))) float;

// ---------------------------------------------------------------------------
// fp32 -> f16 elementwise cast (n multiple of 1024)
// ---------------------------------------------------------------------------
__global__ __launch_bounds__(256)
void cast_f32_f16(const float* __restrict__ src, _Float16* __restrict__ dst)
{
    int i = (blockIdx.x * 256 + threadIdx.x) * 4;
    float4 v = *(const float4*)(src + i);
    half4v h = { (_Float16)v.x, (_Float16)v.y, (_Float16)v.z, (_Float16)v.w };
    *(half4v*)(dst + i) = h;
}

// ---------------------------------------------------------------------------
// W [K][N] fp32  ->  Wt [N][K] f16   (32x32 LDS tile transpose)
// ---------------------------------------------------------------------------
__global__ __launch_bounds__(256)
void transpose_cast(const float* __restrict__ W, _Float16* __restrict__ Wt,
                    int K, int N)
{
    __shared__ float T[32][33];
    const int n0 = blockIdx.x * 32, k0 = blockIdx.y * 32;
    const int t = threadIdx.x;
    const int r = t >> 3, c4 = (t & 7) * 4;
    float4 w = *(const float4*)(W + (size_t)(k0 + r) * N + n0 + c4);
    T[r][c4 + 0] = w.x; T[r][c4 + 1] = w.y;
    T[r][c4 + 2] = w.z; T[r][c4 + 3] = w.w;
    __syncthreads();
    half4v h = { (_Float16)T[c4 + 0][r], (_Float16)T[c4 + 1][r],
                 (_Float16)T[c4 + 2][r], (_Float16)T[c4 + 3][r] };
    *(half4v*)(Wt + (size_t)(n0 + r) * K + k0 + c4) = h;
}

// ---------------------------------------------------------------------------
// f16 MFMA GEMM: C[M,N] = X[M,K] @ Wt[N,K]^T + bias.  128x128x32 tile,
// 4 waves, 64x64 per wave via 4x4 grid of 16x16x32 MFMAs. fp32 accumulate.
// ---------------------------------------------------------------------------
template <bool OUT_F16>
__global__ __launch_bounds__(256, 2)
void hgemm_bias(const _Float16* __restrict__ X, const _Float16* __restrict__ Wt,
                const float* __restrict__ bias, void* __restrict__ Cout,
                int M, int N, int K)
{
    __shared__ _Float16 As[128][40];   // [m][k]  (pad 40: 16B rows, 2-way banks)
    __shared__ _Float16 Bs[128][40];   // [n][k]

    const int tid  = threadIdx.x;
    const int wave = tid >> 6, lane = tid & 63;
    const int quad = lane >> 4, l15 = lane & 15;
    const int wm = (wave >> 1) * 64, wn = (wave & 1) * 64;
    const int m0 = blockIdx.y * 128, n0 = blockIdx.x * 128;

    // staging map: each thread stages one 32-elem k-slab half of a row
    const int srow = tid >> 1, skq = (tid & 1) * 16;
    const _Float16* Xp = X  + (size_t)(m0 + srow) * K + skq;
    const _Float16* Wp = Wt + (size_t)(n0 + srow) * K + skq;

    f32x4 acc[4][4] = {};

    half8 a0 = *(const half8*)(Xp);
    half8 a1 = *(const half8*)(Xp + 8);
    half8 b0 = *(const half8*)(Wp);
    half8 b1 = *(const half8*)(Wp + 8);

    for (int k0 = 0; k0 < K; k0 += 32) {
        *(half8*)&As[srow][skq]     = a0;
        *(half8*)&As[srow][skq + 8] = a1;
        *(half8*)&Bs[srow][skq]     = b0;
        *(half8*)&Bs[srow][skq + 8] = b1;
        __syncthreads();

        if (k0 + 32 < K) {                      // register prefetch of next tile
            a0 = *(const half8*)(Xp + k0 + 32);
            a1 = *(const half8*)(Xp + k0 + 40);
            b0 = *(const half8*)(Wp + k0 + 32);
            b1 = *(const half8*)(Wp + k0 + 40);
        }

        half8 af[4], bf[4];
#pragma unroll
        for (int mt = 0; mt < 4; ++mt)
            af[mt] = *(const half8*)&As[wm + mt * 16 + l15][quad * 8];
#pragma unroll
        for (int nt = 0; nt < 4; ++nt)
            bf[nt] = *(const half8*)&Bs[wn + nt * 16 + l15][quad * 8];
#pragma unroll
        for (int mt = 0; mt < 4; ++mt)
#pragma unroll
            for (int nt = 0; nt < 4; ++nt)
                acc[mt][nt] = __builtin_amdgcn_mfma_f32_16x16x32_f16(
                    af[mt], bf[nt], acc[mt][nt], 0, 0, 0);
        __syncthreads();
    }

    // epilogue: C/D layout col=l15, row=quad*4+reg
#pragma unroll
    for (int nt = 0; nt < 4; ++nt) {
        const int c = n0 + wn + nt * 16 + l15;
        const float bv = bias[c];
#pragma unroll
        for (int mt = 0; mt < 4; ++mt)
#pragma unroll
            for (int reg = 0; reg < 4; ++reg) {
                const int r = m0 + wm + mt * 16 + quad * 4 + reg;
                const float v = acc[mt][nt][reg] + bv;
                if (OUT_F16)
                    ((_Float16*)Cout)[(size_t)r * N + c] = (_Float16)v;
                else
                    ((float*)Cout)[(size_t)r * N + c] = v;
            }
    }
}

// ---------------------------------------------------------------------------
// MFMA flash attention. Grid (S/64, B*H), 256 threads = 4 waves.
// Wave w owns q-rows qt*64 + w*16 .. +15 (Q frags live in registers).
// Per kt: stage K natural / V transposed in LDS; S = QK^T via MFMA;
// per-quad shuffle online-softmax; P -> per-wave LDS -> A-frags; PV via MFMA.
// ---------------------------------------------------------------------------
__global__ __launch_bounds__(256, 4)
void attn_fa_mfma(const _Float16* __restrict__ qkv, _Float16* __restrict__ outh)
{
    __shared__ _Float16 Ks[64][72];      // [krow][d]
    __shared__ _Float16 Vt[64][72];      // [d][krow]
    __shared__ _Float16 Ps[4][16][72];   // per-wave P [qrow][krow]

    const int qt = blockIdx.x, bh = blockIdx.y;
    const int b = bh >> 4, h = bh & 15;
    const int tid  = threadIdx.x;
    const int wave = tid >> 6, lane = tid & 63;
    const int quad = lane >> 4, l15 = lane & 15;
    const size_t row0 = (size_t)b * S_LEN;
    const float scale = 1.0f / 16.0f;    // 1/sqrt(64)/LAYER_IDX

    // Q fragments (A-layout: m=l15, k=quad*8+j), two 32-k chunks
    half8 qf[2];
    {
        const size_t qrow = row0 + qt * 64 + wave * 16 + l15;
        const _Float16* qp = qkv + qrow * QKV_N + h * HD + quad * 8;
        qf[0] = *(const half8*)(qp);
        qf[1] = *(const half8*)(qp + 32);
    }

    f32x4 o_acc[4] = {};
    float m_i[4], l_i[4];
#pragma unroll
    for (int r = 0; r < 4; ++r) { m_i[r] = -1e30f; l_i[r] = 0.0f; }

    const int sr = tid >> 2, sdq = (tid & 3) * 16;   // staging map

    for (int kt = 0; kt <= qt; ++kt) {
        __syncthreads();   // previous iteration done with Ks/Vt
        {
            const _Float16* src = qkv + (row0 + kt * 64 + sr) * QKV_N + h * HD;
            half8 k0 = *(const half8*)(src + EMB + sdq);
            half8 k1 = *(const half8*)(src + EMB + sdq + 8);
            *(half8*)&Ks[sr][sdq]     = k0;
            *(half8*)&Ks[sr][sdq + 8] = k1;
            half8 v0 = *(const half8*)(src + 2 * EMB + sdq);
            half8 v1 = *(const half8*)(src + 2 * EMB + sdq + 8);
#pragma unroll
            for (int j = 0; j < 8; ++j) {            // transpose V into LDS
                Vt[sdq + j][sr]     = v0[j];
                Vt[sdq + 8 + j][sr] = v1[j];
            }
        }
        __syncthreads();

        // ---- S = Q K^T : 4 col-tiles x 2 k-chunks ----
        f32x4 s[4] = {};
#pragma unroll
        for (int nt = 0; nt < 4; ++nt) {
#pragma unroll
            for (int c = 0; c < 2; ++c) {
                half8 kf = *(const half8*)&Ks[nt * 16 + l15][c * 32 + quad * 8];
                s[nt] = __builtin_amdgcn_mfma_f32_16x16x32_f16(qf[c], kf, s[nt], 0, 0, 0);
            }
        }

        // ---- scale + causal mask (C layout: col=l15, row=quad*4+reg) ----
        if (kt == qt) {
            const int rbase = quad * 4;
#pragma unroll
            for (int nt = 0; nt < 4; ++nt)
#pragma unroll
                for (int reg = 0; reg < 4; ++reg) {
                    const int col = nt * 16 + l15;
                    s[nt][reg] = (col > wave * 16 + rbase + reg)
                                     ? MASKED_BIAS : s[nt][reg] * scale;
                }
        } else {
#pragma unroll
            for (int nt = 0; nt < 4; ++nt)
#pragma unroll
                for (int reg = 0; reg < 4; ++reg) s[nt][reg] *= scale;
        }

        // ---- online softmax (reduce across 16 lanes of the quad) ----
#pragma unroll
        for (int reg = 0; reg < 4; ++reg) {
            float rm = fmaxf(fmaxf(s[0][reg], s[1][reg]),
                             fmaxf(s[2][reg], s[3][reg]));
            rm = fmaxf(rm, __shfl_xor(rm, 1));
            rm = fmaxf(rm, __shfl_xor(rm, 2));
            rm = fmaxf(rm, __shfl_xor(rm, 4));
            rm = fmaxf(rm, __shfl_xor(rm, 8));
            const float mnew  = fmaxf(m_i[reg], rm);
            const float alpha = __expf(m_i[reg] - mnew);
            float p[4], rs = 0.0f;
#pragma unroll
            for (int nt = 0; nt < 4; ++nt) {
                p[nt] = __expf(s[nt][reg] - mnew);
                rs += p[nt];
            }
            rs += __shfl_xor(rs, 1);
            rs += __shfl_xor(rs, 2);
            rs += __shfl_xor(rs, 4);
            rs += __shfl_xor(rs, 8);
            l_i[reg] = l_i[reg] * alpha + rs;
            m_i[reg] = mnew;
#pragma unroll
            for (int nt = 0; nt < 4; ++nt) {
                o_acc[nt][reg] *= alpha;
                Ps[wave][quad * 4 + reg][nt * 16 + l15] = (_Float16)p[nt];
            }
        }

        // ---- O += P @ V  (P via per-wave LDS round-trip; no barrier needed) ----
        half8 af0 = *(const half8*)&Ps[wave][l15][quad * 8];
        half8 af1 = *(const half8*)&Ps[wave][l15][32 + quad * 8];
#pragma unroll
        for (int nt = 0; nt < 4; ++nt) {
            half8 bf0 = *(const half8*)&Vt[nt * 16 + l15][quad * 8];
            half8 bf1 = *(const half8*)&Vt[nt * 16 + l15][32 + quad * 8];
            o_acc[nt] = __builtin_amdgcn_mfma_f32_16x16x32_f16(af0, bf0, o_acc[nt], 0, 0, 0);
            o_acc[nt] = __builtin_amdgcn_mfma_f32_16x16x32_f16(af1, bf1, o_acc[nt], 0, 0, 0);
        }
    }

    // ---- normalize, write f16 [B*S, E] ----
#pragma unroll
    for (int reg = 0; reg < 4; ++reg) {
        const float inv = 1.0f / l_i[reg];
        const size_t r = row0 + qt * 64 + wave * 16 + quad * 4 + reg;
#pragma unroll
        for (int nt = 0; nt < 4; ++nt)
            outh[r * EMB + h * HD + nt * 16 + l15] =
                (_Float16)(o_acc[nt][reg] * inv);
    }
}

// ---------------------------------------------------------------------------
extern "C" void kernel_launch(void* const* d_in, const int* in_sizes, int n_in,
                              void* d_out, int out_size, void* d_ws, size_t ws_size,
                              hipStream_t stream)
{
    const float* hidden = (const float*)d_in[0];   // [B,S,E]
    const float* w_attn = (const float*)d_in[1];   // [E,3E]
    const float* b_attn = (const float*)d_in[2];   // [3E]
    const float* w_proj = (const float*)d_in[3];   // [E,E]
    const float* b_proj = (const float*)d_in[4];   // [E]

    _Float16* hidden_h = (_Float16*)d_ws;                        // 4M elems
    _Float16* wattn_t  = hidden_h + (size_t)MROWS * EMB;         // 3M  [3072][1024]
    _Float16* wproj_t  = wattn_t + (size_t)EMB * QKV_N;          // 1M  [1024][1024]
    _Float16* qkv_h    = wproj_t + (size_t)EMB * EMB;            // 12M [4096][3072]
    _Float16* attn_h   = qkv_h + (size_t)MROWS * QKV_N;          // 4M  [4096][1024]
    // total 24M f16 = 48 MB of d_ws

    cast_f32_f16<<<(MROWS * EMB) / 1024, 256, 0, stream>>>(hidden, hidden_h);
    transpose_cast<<<dim3(QKV_N / 32, EMB / 32), 256, 0, stream>>>(
        w_attn, wattn_t, EMB, QKV_N);
    transpose_cast<<<dim3(EMB / 32, EMB / 32), 256, 0, stream>>>(
        w_proj, wproj_t, EMB, EMB);

    hgemm_bias<true><<<dim3(QKV_N / 128, MROWS / 128), 256, 0, stream>>>(
        hidden_h, wattn_t, b_attn, qkv_h, MROWS, QKV_N, EMB);

    attn_fa_mfma<<<dim3(S_LEN / 64, B_DIM * NH), 256, 0, stream>>>(qkv_h, attn_h);

    hgemm_bias<false><<<dim3(EMB / 128, MROWS / 128), 256, 0, stream>>>(
        attn_h, wproj_t, b_proj, d_out, MROWS, EMB, EMB);
}

// Round 3
// 234.459 us; speedup vs baseline: 6.7985x; 1.1766x over previous
//
#include <hip/hip_runtime.h>
#include <cstddef>

#define B_DIM   2
#define S_LEN   2048
#define EMB     1024
#define NH      16
#define HD      64
#define QKV_N   3072
#define MROWS   (B_DIM * S_LEN)

using half8  = __attribute__((ext_vector_type(8))) _Float16;
using half4v = __attribute__((ext_vector_type(4))) _Float16;
using f32x4  = __attribute__((ext_vector_type(4))) float;

// ---------------------------------------------------------------------------
// fp32 -> f16 elementwise cast
// ---------------------------------------------------------------------------
__global__ __launch_bounds__(256)
void cast_f32_f16(const float* __restrict__ src, _Float16* __restrict__ dst)
{
    int i = (blockIdx.x * 256 + threadIdx.x) * 4;
    float4 v = *(const float4*)(src + i);
    half4v h = { (_Float16)v.x, (_Float16)v.y, (_Float16)v.z, (_Float16)v.w };
    *(half4v*)(dst + i) = h;
}

// ---------------------------------------------------------------------------
// W [K][N] fp32  ->  Wt [N][K] f16   (32x32 LDS tile transpose)
// ---------------------------------------------------------------------------
__global__ __launch_bounds__(256)
void transpose_cast(const float* __restrict__ W, _Float16* __restrict__ Wt,
                    int K, int N)
{
    __shared__ float T[32][33];
    const int n0 = blockIdx.x * 32, k0 = blockIdx.y * 32;
    const int t = threadIdx.x;
    const int r = t >> 3, c4 = (t & 7) * 4;
    float4 w = *(const float4*)(W + (size_t)(k0 + r) * N + n0 + c4);
    T[r][c4 + 0] = w.x; T[r][c4 + 1] = w.y;
    T[r][c4 + 2] = w.z; T[r][c4 + 3] = w.w;
    __syncthreads();
    half4v h = { (_Float16)T[c4 + 0][r], (_Float16)T[c4 + 1][r],
                 (_Float16)T[c4 + 2][r], (_Float16)T[c4 + 3][r] };
    *(half4v*)(Wt + (size_t)(n0 + r) * K + k0 + c4) = h;
}

// ---------------------------------------------------------------------------
// V section of qkv_h  ->  vt[bh][d][s]  (64x64 f16 tile transpose)
// grid (S/64, B*H)
// ---------------------------------------------------------------------------
__global__ __launch_bounds__(256)
void transpose_v(const _Float16* __restrict__ qkv, _Float16* __restrict__ vt)
{
    __shared__ _Float16 T[64][66];
    const int st = blockIdx.x, bh = blockIdx.y;
    const int b = bh >> 4, h = bh & 15;
    const int t = threadIdx.x;
    const int sr = t >> 2, dc = (t & 3) * 16;

    const _Float16* src = qkv + ((size_t)(b * S_LEN + st * 64 + sr)) * QKV_N
                              + 2 * EMB + h * HD + dc;
    half8 v0 = *(const half8*)(src);
    half8 v1 = *(const half8*)(src + 8);
#pragma unroll
    for (int j = 0; j < 8; ++j) { T[sr][dc + j] = v0[j]; T[sr][dc + 8 + j] = v1[j]; }
    __syncthreads();

    const int dr = t >> 2, sc = (t & 3) * 16;
    half8 o0, o1;
#pragma unroll
    for (int j = 0; j < 8; ++j) { o0[j] = T[sc + j][dr]; o1[j] = T[sc + 8 + j][dr]; }
    _Float16* dst = vt + (size_t)bh * HD * S_LEN + (size_t)dr * S_LEN + st * 64 + sc;
    *(half8*)(dst)     = o0;
    *(half8*)(dst + 8) = o1;
}

// ---------------------------------------------------------------------------
// f16 MFMA GEMM: C[M,N] = X[M,K] @ Wt[N,K]^T + bias.  128x128x32 tile.
// ---------------------------------------------------------------------------
template <bool OUT_F16>
__global__ __launch_bounds__(256, 2)
void hgemm_bias(const _Float16* __restrict__ X, const _Float16* __restrict__ Wt,
                const float* __restrict__ bias, void* __restrict__ Cout,
                int M, int N, int K)
{
    __shared__ _Float16 As[128][40];
    __shared__ _Float16 Bs[128][40];

    const int tid  = threadIdx.x;
    const int wave = tid >> 6, lane = tid & 63;
    const int quad = lane >> 4, l15 = lane & 15;
    const int wm = (wave >> 1) * 64, wn = (wave & 1) * 64;
    const int m0 = blockIdx.y * 128, n0 = blockIdx.x * 128;

    const int srow = tid >> 1, skq = (tid & 1) * 16;
    const _Float16* Xp = X  + (size_t)(m0 + srow) * K + skq;
    const _Float16* Wp = Wt + (size_t)(n0 + srow) * K + skq;

    f32x4 acc[4][4] = {};

    half8 a0 = *(const half8*)(Xp);
    half8 a1 = *(const half8*)(Xp + 8);
    half8 b0 = *(const half8*)(Wp);
    half8 b1 = *(const half8*)(Wp + 8);

    for (int k0 = 0; k0 < K; k0 += 32) {
        *(half8*)&As[srow][skq]     = a0;
        *(half8*)&As[srow][skq + 8] = a1;
        *(half8*)&Bs[srow][skq]     = b0;
        *(half8*)&Bs[srow][skq + 8] = b1;
        __syncthreads();

        if (k0 + 32 < K) {
            a0 = *(const half8*)(Xp + k0 + 32);
            a1 = *(const half8*)(Xp + k0 + 40);
            b0 = *(const half8*)(Wp + k0 + 32);
            b1 = *(const half8*)(Wp + k0 + 40);
        }

        half8 af[4], bf[4];
#pragma unroll
        for (int mt = 0; mt < 4; ++mt)
            af[mt] = *(const half8*)&As[wm + mt * 16 + l15][quad * 8];
#pragma unroll
        for (int nt = 0; nt < 4; ++nt)
            bf[nt] = *(const half8*)&Bs[wn + nt * 16 + l15][quad * 8];
#pragma unroll
        for (int mt = 0; mt < 4; ++mt)
#pragma unroll
            for (int nt = 0; nt < 4; ++nt)
                acc[mt][nt] = __builtin_amdgcn_mfma_f32_16x16x32_f16(
                    af[mt], bf[nt], acc[mt][nt], 0, 0, 0);
        __syncthreads();
    }

#pragma unroll
    for (int nt = 0; nt < 4; ++nt) {
        const int c = n0 + wn + nt * 16 + l15;
        const float bv = bias[c];
#pragma unroll
        for (int mt = 0; mt < 4; ++mt)
#pragma unroll
            for (int reg = 0; reg < 4; ++reg) {
                const int r = m0 + wm + mt * 16 + quad * 4 + reg;
                const float v = acc[mt][nt][reg] + bv;
                if (OUT_F16)
                    ((_Float16*)Cout)[(size_t)r * N + c] = (_Float16)v;
                else
                    ((float*)Cout)[(size_t)r * N + c] = v;
            }
    }
}

// ---------------------------------------------------------------------------
// MFMA flash attention v2. 512 blocks (decoded for CU load balance), 4 waves.
// q-tile = 128 rows; wave owns 32 rows (2 m-tiles). K from qkv_h, V from vt
// (pre-transposed) -> all staging is vector loads/stores. exp2-domain softmax
// with scale*log2e folded into Q.
// ---------------------------------------------------------------------------
__global__ __launch_bounds__(256, 2)
void attn_fa_mfma2(const _Float16* __restrict__ qkv,
                   const _Float16* __restrict__ vt,
                   _Float16* __restrict__ outh)
{
    __shared__ _Float16 Ks[64][72];       // [krow][d]
    __shared__ _Float16 Vs[64][72];       // [d][krow]  (from vt, already transposed)
    __shared__ _Float16 Ps[4][32][68];    // per-wave P [qrow][krow]

    // block decode: n and n+256 get complementary qt -> balanced CUs
    const int n    = blockIdx.x;
    const int half = n >> 8, idx = n & 255;
    const int bh   = idx >> 3, jj = idx & 7;
    const int qt   = half ? (15 - jj) : jj;
    const int b = bh >> 4, h = bh & 15;

    const int tid  = threadIdx.x;
    const int wave = tid >> 6, lane = tid & 63;
    const int quad = lane >> 4, l15 = lane & 15;
    const size_t row0 = (size_t)b * S_LEN;

    // Q fragments, pre-scaled by log2(e)/16 (scale + exp->exp2 fold)
    const _Float16 qscale = (_Float16)0.0901684400555602f;
    half8 qf[2][2];
#pragma unroll
    for (int mt = 0; mt < 2; ++mt) {
        const size_t qrow = row0 + qt * 128 + wave * 32 + mt * 16 + l15;
        const _Float16* qp = qkv + qrow * QKV_N + h * HD + quad * 8;
#pragma unroll
        for (int c = 0; c < 2; ++c) {
            half8 q = *(const half8*)(qp + c * 32);
#pragma unroll
            for (int j = 0; j < 8; ++j) q[j] = q[j] * qscale;
            qf[mt][c] = q;
        }
    }

    f32x4 o_acc[2][4] = {};
    float m_i[2][4], l_i[2][4];
#pragma unroll
    for (int mt = 0; mt < 2; ++mt)
#pragma unroll
        for (int r = 0; r < 4; ++r) { m_i[mt][r] = -1e30f; l_i[mt][r] = 0.0f; }

    const int sr = tid >> 2, sdq = (tid & 3) * 16;   // staging map
    const _Float16* vbase = vt + (size_t)bh * HD * S_LEN;

    const int kt_end = 2 * qt + 1;
    for (int kt = 0; kt <= kt_end; ++kt) {
        __syncthreads();
        {   // stage K (natural rows) and V (pre-transposed rows) - all vector
            const _Float16* ksrc = qkv + (row0 + kt * 64 + sr) * QKV_N + EMB + h * HD + sdq;
            half8 k0 = *(const half8*)(ksrc);
            half8 k1 = *(const half8*)(ksrc + 8);
            *(half8*)&Ks[sr][sdq]     = k0;
            *(half8*)&Ks[sr][sdq + 8] = k1;
            const _Float16* vsrc = vbase + (size_t)sr * S_LEN + kt * 64 + sdq;
            half8 v0 = *(const half8*)(vsrc);
            half8 v1 = *(const half8*)(vsrc + 8);
            *(half8*)&Vs[sr][sdq]     = v0;
            *(half8*)&Vs[sr][sdq + 8] = v1;
        }
        __syncthreads();

        // ---- S = Q K^T  (2 m-tiles x 4 n-tiles x 2 k-chunks) ----
        f32x4 s[2][4] = {};
#pragma unroll
        for (int c = 0; c < 2; ++c)
#pragma unroll
            for (int nt = 0; nt < 4; ++nt) {
                half8 kf = *(const half8*)&Ks[nt * 16 + l15][c * 32 + quad * 8];
#pragma unroll
                for (int mt = 0; mt < 2; ++mt)
                    s[mt][nt] = __builtin_amdgcn_mfma_f32_16x16x32_f16(
                        qf[mt][c], kf, s[mt][nt], 0, 0, 0);
            }

        // ---- causal mask (only the last two kt tiles can touch diagonal) ----
        if (kt >= 2 * qt) {
#pragma unroll
            for (int mt = 0; mt < 2; ++mt)
#pragma unroll
                for (int nt = 0; nt < 4; ++nt) {
                    const int col = kt * 64 + nt * 16 + l15;
                    const int rowb = qt * 128 + wave * 32 + mt * 16 + quad * 4;
#pragma unroll
                    for (int reg = 0; reg < 4; ++reg)
                        if (col > rowb + reg) s[mt][nt][reg] = -1e30f;
                }
        }

        // ---- online softmax in exp2 domain ----
#pragma unroll
        for (int mt = 0; mt < 2; ++mt)
#pragma unroll
            for (int reg = 0; reg < 4; ++reg) {
                float rm = fmaxf(fmaxf(s[mt][0][reg], s[mt][1][reg]),
                                 fmaxf(s[mt][2][reg], s[mt][3][reg]));
                rm = fmaxf(rm, __shfl_xor(rm, 1));
                rm = fmaxf(rm, __shfl_xor(rm, 2));
                rm = fmaxf(rm, __shfl_xor(rm, 4));
                rm = fmaxf(rm, __shfl_xor(rm, 8));
                const float mnew  = fmaxf(m_i[mt][reg], rm);
                const float alpha = __builtin_amdgcn_exp2f(m_i[mt][reg] - mnew);
                float p[4], rs = 0.0f;
#pragma unroll
                for (int nt = 0; nt < 4; ++nt) {
                    p[nt] = __builtin_amdgcn_exp2f(s[mt][nt][reg] - mnew);
                    rs += p[nt];
                }
                rs += __shfl_xor(rs, 1);
                rs += __shfl_xor(rs, 2);
                rs += __shfl_xor(rs, 4);
                rs += __shfl_xor(rs, 8);
                l_i[mt][reg] = l_i[mt][reg] * alpha + rs;
                m_i[mt][reg] = mnew;
#pragma unroll
                for (int nt = 0; nt < 4; ++nt) {
                    o_acc[mt][nt][reg] *= alpha;
                    Ps[wave][mt * 16 + quad * 4 + reg][nt * 16 + l15] = (_Float16)p[nt];
                }
            }

        // ---- O += P @ V  (per-wave LDS round-trip, no barrier) ----
#pragma unroll
        for (int mt = 0; mt < 2; ++mt) {
            half8 af0 = *(const half8*)&Ps[wave][mt * 16 + l15][quad * 8];
            half8 af1 = *(const half8*)&Ps[wave][mt * 16 + l15][32 + quad * 8];
#pragma unroll
            for (int nt = 0; nt < 4; ++nt) {
                half8 bf0 = *(const half8*)&Vs[nt * 16 + l15][quad * 8];
                half8 bf1 = *(const half8*)&Vs[nt * 16 + l15][32 + quad * 8];
                o_acc[mt][nt] = __builtin_amdgcn_mfma_f32_16x16x32_f16(af0, bf0, o_acc[mt][nt], 0, 0, 0);
                o_acc[mt][nt] = __builtin_amdgcn_mfma_f32_16x16x32_f16(af1, bf1, o_acc[mt][nt], 0, 0, 0);
            }
        }
    }

    // ---- normalize, write f16 [B*S, E] ----
#pragma unroll
    for (int mt = 0; mt < 2; ++mt)
#pragma unroll
        for (int reg = 0; reg < 4; ++reg) {
            const float inv = 1.0f / l_i[mt][reg];
            const size_t r = row0 + qt * 128 + wave * 32 + mt * 16 + quad * 4 + reg;
#pragma unroll
            for (int nt = 0; nt < 4; ++nt)
                outh[r * EMB + h * HD + nt * 16 + l15] =
                    (_Float16)(o_acc[mt][nt][reg] * inv);
        }
}

// ---------------------------------------------------------------------------
extern "C" void kernel_launch(void* const* d_in, const int* in_sizes, int n_in,
                              void* d_out, int out_size, void* d_ws, size_t ws_size,
                              hipStream_t stream)
{
    const float* hidden = (const float*)d_in[0];
    const float* w_attn = (const float*)d_in[1];
    const float* b_attn = (const float*)d_in[2];
    const float* w_proj = (const float*)d_in[3];
    const float* b_proj = (const float*)d_in[4];

    _Float16* hidden_h = (_Float16*)d_ws;                        // 4M
    _Float16* wattn_t  = hidden_h + (size_t)MROWS * EMB;         // 3M
    _Float16* wproj_t  = wattn_t + (size_t)EMB * QKV_N;          // 1M
    _Float16* qkv_h    = wproj_t + (size_t)EMB * EMB;            // 12M
    _Float16* attn_h   = qkv_h + (size_t)MROWS * QKV_N;          // 4M
    _Float16* vt       = attn_h + (size_t)MROWS * EMB;           // 4M
    // total 28M f16 = 56 MB

    cast_f32_f16<<<(MROWS * EMB) / 1024, 256, 0, stream>>>(hidden, hidden_h);
    transpose_cast<<<dim3(QKV_N / 32, EMB / 32), 256, 0, stream>>>(
        w_attn, wattn_t, EMB, QKV_N);
    transpose_cast<<<dim3(EMB / 32, EMB / 32), 256, 0, stream>>>(
        w_proj, wproj_t, EMB, EMB);

    hgemm_bias<true><<<dim3(QKV_N / 128, MROWS / 128), 256, 0, stream>>>(
        hidden_h, wattn_t, b_attn, qkv_h, MROWS, QKV_N, EMB);

    transpose_v<<<dim3(S_LEN / 64, B_DIM * NH), 256, 0, stream>>>(qkv_h, vt);

    attn_fa_mfma2<<<dim3(512), 256, 0, stream>>>(qkv_h, vt, attn_h);

    hgemm_bias<false><<<dim3(EMB / 128, MROWS / 128), 256, 0, stream>>>(
        attn_h, wproj_t, b_proj, d_out, MROWS, EMB, EMB);
}

// Round 4
// 221.643 us; speedup vs baseline: 7.1915x; 1.0578x over previous
//
#include <hip/hip_runtime.h>
#include <cstddef>
#include <cstdint>

#define B_DIM   2
#define S_LEN   2048
#define EMB     1024
#define NH      16
#define HD      64
#define QKV_N   3072
#define MROWS   (B_DIM * S_LEN)

using half8  = __attribute__((ext_vector_type(8))) _Float16;
using half4v = __attribute__((ext_vector_type(4))) _Float16;
using f32x4  = __attribute__((ext_vector_type(4))) float;

#if defined(__has_builtin)
#if __has_builtin(__builtin_amdgcn_global_load_lds)
#define HAS_GLL 1
#endif
#endif

// Stage 16B/lane: async direct-to-LDS when available; lane deposits at
// lds_base + lane*16 (wave-uniform base). Fallback replicates the layout.
__device__ __forceinline__ void stage16(const _Float16* g, _Float16* lds_base, int lane)
{
#ifdef HAS_GLL
    (void)lane;
    __builtin_amdgcn_global_load_lds(
        (const __attribute__((address_space(1))) unsigned int*)g,
        (__attribute__((address_space(3))) unsigned int*)lds_base, 16, 0, 0);
#else
    *(half8*)(lds_base + lane * 8) = *(const half8*)g;
#endif
}

// ---------------------------------------------------------------------------
// fp32 -> f16 elementwise cast
// ---------------------------------------------------------------------------
__global__ __launch_bounds__(256)
void cast_f32_f16(const float* __restrict__ src, _Float16* __restrict__ dst)
{
    int i = (blockIdx.x * 256 + threadIdx.x) * 4;
    float4 v = *(const float4*)(src + i);
    half4v h = { (_Float16)v.x, (_Float16)v.y, (_Float16)v.z, (_Float16)v.w };
    *(half4v*)(dst + i) = h;
}

// ---------------------------------------------------------------------------
// W [K][N] fp32  ->  Wt [N][K] f16
// ---------------------------------------------------------------------------
__global__ __launch_bounds__(256)
void transpose_cast(const float* __restrict__ W, _Float16* __restrict__ Wt,
                    int K, int N)
{
    __shared__ float T[32][33];
    const int n0 = blockIdx.x * 32, k0 = blockIdx.y * 32;
    const int t = threadIdx.x;
    const int r = t >> 3, c4 = (t & 7) * 4;
    float4 w = *(const float4*)(W + (size_t)(k0 + r) * N + n0 + c4);
    T[r][c4 + 0] = w.x; T[r][c4 + 1] = w.y;
    T[r][c4 + 2] = w.z; T[r][c4 + 3] = w.w;
    __syncthreads();
    half4v h = { (_Float16)T[c4 + 0][r], (_Float16)T[c4 + 1][r],
                 (_Float16)T[c4 + 2][r], (_Float16)T[c4 + 3][r] };
    *(half4v*)(Wt + (size_t)(n0 + r) * K + k0 + c4) = h;
}

// ---------------------------------------------------------------------------
// V section of qkv_h -> vt[bh][d][s]
// ---------------------------------------------------------------------------
__global__ __launch_bounds__(256)
void transpose_v(const _Float16* __restrict__ qkv, _Float16* __restrict__ vt)
{
    __shared__ _Float16 T[64][66];
    const int st = blockIdx.x, bh = blockIdx.y;
    const int b = bh >> 4, h = bh & 15;
    const int t = threadIdx.x;
    const int sr = t >> 2, dc = (t & 3) * 16;

    const _Float16* src = qkv + ((size_t)(b * S_LEN + st * 64 + sr)) * QKV_N
                              + 2 * EMB + h * HD + dc;
    half8 v0 = *(const half8*)(src);
    half8 v1 = *(const half8*)(src + 8);
#pragma unroll
    for (int j = 0; j < 8; ++j) { T[sr][dc + j] = v0[j]; T[sr][dc + 8 + j] = v1[j]; }
    __syncthreads();

    const int dr = t >> 2, sc = (t & 3) * 16;
    half8 o0, o1;
#pragma unroll
    for (int j = 0; j < 8; ++j) { o0[j] = T[sc + j][dr]; o1[j] = T[sc + 8 + j][dr]; }
    _Float16* dst = vt + (size_t)bh * HD * S_LEN + (size_t)dr * S_LEN + st * 64 + sc;
    *(half8*)(dst)     = o0;
    *(half8*)(dst + 8) = o1;
}

// ---------------------------------------------------------------------------
// m97-style f16 MFMA GEMM. Tile BM x 128 x 32, BM = MT*32.
// Unpadded LDS rows (64 B) so global_load_lds lane-contiguous layout matches.
// ---------------------------------------------------------------------------
template <int MT, int MINW, bool OUT_F16>
__global__ __launch_bounds__(256, MINW)
void hgemm_lds(const _Float16* __restrict__ X, const _Float16* __restrict__ Wt,
               const float* __restrict__ bias, void* __restrict__ Cout,
               int M, int N, int K)
{
    constexpr int BM = MT * 32;
    constexpr int CA = BM / 64;            // A 64-row chunks (1 or 2)
    __shared__ _Float16 As[BM][32];
    __shared__ _Float16 Bs[128][32];

    const int tid  = threadIdx.x;
    const int wave = tid >> 6, lane = tid & 63;
    const int quad = lane >> 4, l15 = lane & 15;
    const int wm = (wave >> 1) * (MT * 16);
    const int wn = (wave & 1) * 64;
    const int m0 = blockIdx.y * BM, n0 = blockIdx.x * 128;

    const int lrow = lane >> 2;            // 0..15 within the wave's 16 rows
    const int lcol = (lane & 3) * 8;       // f16 col within the 32-k slab

    const _Float16* xg[CA];
#pragma unroll
    for (int t = 0; t < CA; ++t)
        xg[t] = X + (size_t)(m0 + t * 64 + wave * 16 + lrow) * K + lcol;
    const _Float16* wg[2];
#pragma unroll
    for (int t = 0; t < 2; ++t)
        wg[t] = Wt + (size_t)(n0 + t * 64 + wave * 16 + lrow) * K + lcol;

    f32x4 acc[MT][4] = {};

    for (int k0 = 0; k0 < K; k0 += 32) {
#pragma unroll
        for (int t = 0; t < CA; ++t)
            stage16(xg[t] + k0, &As[t * 64 + wave * 16][0], lane);
#pragma unroll
        for (int t = 0; t < 2; ++t)
            stage16(wg[t] + k0, &Bs[t * 64 + wave * 16][0], lane);
        __syncthreads();   // drains vmcnt -> LDS tile ready

        half8 af[MT], bf[4];
#pragma unroll
        for (int mt = 0; mt < MT; ++mt)
            af[mt] = *(const half8*)&As[wm + mt * 16 + l15][quad * 8];
#pragma unroll
        for (int nt = 0; nt < 4; ++nt)
            bf[nt] = *(const half8*)&Bs[wn + nt * 16 + l15][quad * 8];
#pragma unroll
        for (int mt = 0; mt < MT; ++mt)
#pragma unroll
            for (int nt = 0; nt < 4; ++nt)
                acc[mt][nt] = __builtin_amdgcn_mfma_f32_16x16x32_f16(
                    af[mt], bf[nt], acc[mt][nt], 0, 0, 0);
        __syncthreads();   // all reads done before next overwrite
    }

#pragma unroll
    for (int nt = 0; nt < 4; ++nt) {
        const int c = n0 + wn + nt * 16 + l15;
        const float bv = bias[c];
#pragma unroll
        for (int mt = 0; mt < MT; ++mt)
#pragma unroll
            for (int reg = 0; reg < 4; ++reg) {
                const int r = m0 + wm + mt * 16 + quad * 4 + reg;
                const float v = acc[mt][nt][reg] + bv;
                if (OUT_F16)
                    ((_Float16*)Cout)[(size_t)r * N + c] = (_Float16)v;
                else
                    ((float*)Cout)[(size_t)r * N + c] = v;
            }
    }
}

// ---------------------------------------------------------------------------
// MFMA flash attention v3. Grid 1024 (balanced decode), 4 waves.
// q-tile 64 rows (16/wave), k-tile 128 cols. K from qkv_h, V from vt.
// exp2-domain online softmax, scale*log2e folded into Q.
// ---------------------------------------------------------------------------
__global__ __launch_bounds__(256, 3)
void attn_fa_mfma3(const _Float16* __restrict__ qkv,
                   const _Float16* __restrict__ vt,
                   _Float16* __restrict__ outh)
{
    __shared__ _Float16 Ks[128][72];      // [krow][d]
    __shared__ _Float16 Vs[64][136];      // [d][krow]
    __shared__ _Float16 Ps[4][16][136];   // per-wave P [qrow][krow]

    const int n    = blockIdx.x;          // 0..1023
    const int half = n >> 9, idx = n & 511;
    const int bh   = idx >> 4, jj = idx & 15;
    const int qt   = half ? (31 - jj) : jj;   // 64-row q-tile index
    const int b = bh >> 4, h = bh & 15;

    const int tid  = threadIdx.x;
    const int wave = tid >> 6, lane = tid & 63;
    const int quad = lane >> 4, l15 = lane & 15;
    const size_t row0 = (size_t)b * S_LEN;

    // Q fragments, pre-scaled by log2(e)/16
    const _Float16 qscale = (_Float16)0.0901684400555602f;
    half8 qf[2];
    {
        const size_t qrow = row0 + qt * 64 + wave * 16 + l15;
        const _Float16* qp = qkv + qrow * QKV_N + h * HD + quad * 8;
#pragma unroll
        for (int c = 0; c < 2; ++c) {
            half8 q = *(const half8*)(qp + c * 32);
#pragma unroll
            for (int j = 0; j < 8; ++j) q[j] = q[j] * qscale;
            qf[c] = q;
        }
    }

    f32x4 o_acc[4] = {};
    float m_i[4], l_i[4];
#pragma unroll
    for (int r = 0; r < 4; ++r) { m_i[r] = -1e30f; l_i[r] = 0.0f; }

    // staging maps (4 x half8 per thread per matrix)
    const int ksr = tid >> 1, ksc = (tid & 1) * 32;   // K: row 0..127, col 0/32
    const int vsr = tid >> 2, vsc = (tid & 3) * 32;   // V: d 0..63, col slab
    const _Float16* vbase = vt + (size_t)bh * HD * S_LEN;

    const int ktN = (qt + 2) >> 1;
    for (int kt = 0; kt < ktN; ++kt) {
        __syncthreads();
        {
            const _Float16* ksrc = qkv + (row0 + kt * 128 + ksr) * QKV_N
                                       + EMB + h * HD + ksc;
            half8 k0 = *(const half8*)(ksrc);
            half8 k1 = *(const half8*)(ksrc + 8);
            half8 k2 = *(const half8*)(ksrc + 16);
            half8 k3 = *(const half8*)(ksrc + 24);
            *(half8*)&Ks[ksr][ksc]      = k0;
            *(half8*)&Ks[ksr][ksc + 8]  = k1;
            *(half8*)&Ks[ksr][ksc + 16] = k2;
            *(half8*)&Ks[ksr][ksc + 24] = k3;
            const _Float16* vsrc = vbase + (size_t)vsr * S_LEN + kt * 128 + vsc;
            half8 v0 = *(const half8*)(vsrc);
            half8 v1 = *(const half8*)(vsrc + 8);
            half8 v2 = *(const half8*)(vsrc + 16);
            half8 v3 = *(const half8*)(vsrc + 24);
            *(half8*)&Vs[vsr][vsc]      = v0;
            *(half8*)&Vs[vsr][vsc + 8]  = v1;
            *(half8*)&Vs[vsr][vsc + 16] = v2;
            *(half8*)&Vs[vsr][vsc + 24] = v3;
        }
        __syncthreads();

        // ---- S = Q K^T : 8 col-tiles x 2 k-chunks ----
        f32x4 s[8] = {};
#pragma unroll
        for (int c = 0; c < 2; ++c)
#pragma unroll
            for (int nt = 0; nt < 8; ++nt) {
                half8 kf = *(const half8*)&Ks[nt * 16 + l15][c * 32 + quad * 8];
                s[nt] = __builtin_amdgcn_mfma_f32_16x16x32_f16(qf[c], kf, s[nt], 0, 0, 0);
            }

        // ---- causal mask (last tile only) ----
        if (kt == ktN - 1) {
#pragma unroll
            for (int nt = 0; nt < 8; ++nt) {
                const int col  = kt * 128 + nt * 16 + l15;
                const int rowb = qt * 64 + wave * 16 + quad * 4;
#pragma unroll
                for (int reg = 0; reg < 4; ++reg)
                    if (col > rowb + reg) s[nt][reg] = -1e30f;
            }
        }

        // ---- online softmax (exp2 domain) ----
#pragma unroll
        for (int reg = 0; reg < 4; ++reg) {
            float rm = s[0][reg];
#pragma unroll
            for (int nt = 1; nt < 8; ++nt) rm = fmaxf(rm, s[nt][reg]);
            rm = fmaxf(rm, __shfl_xor(rm, 1));
            rm = fmaxf(rm, __shfl_xor(rm, 2));
            rm = fmaxf(rm, __shfl_xor(rm, 4));
            rm = fmaxf(rm, __shfl_xor(rm, 8));
            const float mnew  = fmaxf(m_i[reg], rm);
            const float alpha = __builtin_amdgcn_exp2f(m_i[reg] - mnew);
            float rs = 0.0f;
#pragma unroll
            for (int nt = 0; nt < 8; ++nt) {
                const float p = __builtin_amdgcn_exp2f(s[nt][reg] - mnew);
                rs += p;
                Ps[wave][quad * 4 + reg][nt * 16 + l15] = (_Float16)p;
            }
            rs += __shfl_xor(rs, 1);
            rs += __shfl_xor(rs, 2);
            rs += __shfl_xor(rs, 4);
            rs += __shfl_xor(rs, 8);
            l_i[reg] = l_i[reg] * alpha + rs;
            m_i[reg] = mnew;
#pragma unroll
            for (int dt = 0; dt < 4; ++dt) o_acc[dt][reg] *= alpha;
        }

        // ---- O += P @ V  (per-wave LDS round-trip, no barrier) ----
        half8 af[4];
#pragma unroll
        for (int c = 0; c < 4; ++c)
            af[c] = *(const half8*)&Ps[wave][l15][c * 32 + quad * 8];
#pragma unroll
        for (int dt = 0; dt < 4; ++dt)
#pragma unroll
            for (int c = 0; c < 4; ++c) {
                half8 bf = *(const half8*)&Vs[dt * 16 + l15][c * 32 + quad * 8];
                o_acc[dt] = __builtin_amdgcn_mfma_f32_16x16x32_f16(af[c], bf, o_acc[dt], 0, 0, 0);
            }
    }

    // ---- normalize, write f16 [B*S, E] ----
#pragma unroll
    for (int reg = 0; reg < 4; ++reg) {
        const float inv = 1.0f / l_i[reg];
        const size_t r = row0 + qt * 64 + wave * 16 + quad * 4 + reg;
#pragma unroll
        for (int dt = 0; dt < 4; ++dt)
            outh[r * EMB + h * HD + dt * 16 + l15] =
                (_Float16)(o_acc[dt][reg] * inv);
    }
}

// ---------------------------------------------------------------------------
extern "C" void kernel_launch(void* const* d_in, const int* in_sizes, int n_in,
                              void* d_out, int out_size, void* d_ws, size_t ws_size,
                              hipStream_t stream)
{
    const float* hidden = (const float*)d_in[0];
    const float* w_attn = (const float*)d_in[1];
    const float* b_attn = (const float*)d_in[2];
    const float* w_proj = (const float*)d_in[3];
    const float* b_proj = (const float*)d_in[4];

    _Float16* hidden_h = (_Float16*)d_ws;                        // 4M
    _Float16* wattn_t  = hidden_h + (size_t)MROWS * EMB;         // 3M
    _Float16* wproj_t  = wattn_t + (size_t)EMB * QKV_N;          // 1M
    _Float16* qkv_h    = wproj_t + (size_t)EMB * EMB;            // 12M
    _Float16* attn_h   = qkv_h + (size_t)MROWS * QKV_N;          // 4M
    _Float16* vt       = attn_h + (size_t)MROWS * EMB;           // 4M

    cast_f32_f16<<<(MROWS * EMB) / 1024, 256, 0, stream>>>(hidden, hidden_h);
    transpose_cast<<<dim3(QKV_N / 32, EMB / 32), 256, 0, stream>>>(
        w_attn, wattn_t, EMB, QKV_N);
    transpose_cast<<<dim3(EMB / 32, EMB / 32), 256, 0, stream>>>(
        w_proj, wproj_t, EMB, EMB);

    hgemm_lds<4, 3, true><<<dim3(QKV_N / 128, MROWS / 128), 256, 0, stream>>>(
        hidden_h, wattn_t, b_attn, qkv_h, MROWS, QKV_N, EMB);

    transpose_v<<<dim3(S_LEN / 64, B_DIM * NH), 256, 0, stream>>>(qkv_h, vt);

    attn_fa_mfma3<<<dim3(1024), 256, 0, stream>>>(qkv_h, vt, attn_h);

    hgemm_lds<2, 4, false><<<dim3(EMB / 128, MROWS / 64), 256, 0, stream>>>(
        attn_h, wproj_t, b_proj, d_out, MROWS, EMB, EMB);
}

// Round 5
// 203.334 us; speedup vs baseline: 7.8391x; 1.0900x over previous
//
#include <hip/hip_runtime.h>
#include <cstddef>
#include <cstdint>

#define B_DIM   2
#define S_LEN   2048
#define EMB     1024
#define NH      16
#define HD      64
#define QKV_N   3072
#define MROWS   (B_DIM * S_LEN)

using half8  = __attribute__((ext_vector_type(8))) _Float16;
using half4  = __attribute__((ext_vector_type(4))) _Float16;
using f32x4  = __attribute__((ext_vector_type(4))) float;

#if defined(__has_builtin)
#if __has_builtin(__builtin_amdgcn_global_load_lds)
#define HAS_GLL 1
#endif
#endif

__device__ __forceinline__ void stage16(const _Float16* g, _Float16* lds_base, int lane)
{
#ifdef HAS_GLL
    (void)lane;
    __builtin_amdgcn_global_load_lds(
        (const __attribute__((address_space(1))) unsigned int*)g,
        (__attribute__((address_space(3))) unsigned int*)lds_base, 16, 0, 0);
#else
    *(half8*)(lds_base + lane * 8) = *(const half8*)g;
#endif
}

// ---------------------------------------------------------------------------
// fp32 -> f16 elementwise cast
// ---------------------------------------------------------------------------
__global__ __launch_bounds__(256)
void cast_f32_f16(const float* __restrict__ src, _Float16* __restrict__ dst)
{
    int i = (blockIdx.x * 256 + threadIdx.x) * 4;
    float4 v = *(const float4*)(src + i);
    half4 h = { (_Float16)v.x, (_Float16)v.y, (_Float16)v.z, (_Float16)v.w };
    *(half4*)(dst + i) = h;
}

// ---------------------------------------------------------------------------
// W [K][N] fp32  ->  Wt [N][K] f16
// ---------------------------------------------------------------------------
__global__ __launch_bounds__(256)
void transpose_cast(const float* __restrict__ W, _Float16* __restrict__ Wt,
                    int K, int N)
{
    __shared__ float T[32][33];
    const int n0 = blockIdx.x * 32, k0 = blockIdx.y * 32;
    const int t = threadIdx.x;
    const int r = t >> 3, c4 = (t & 7) * 4;
    float4 w = *(const float4*)(W + (size_t)(k0 + r) * N + n0 + c4);
    T[r][c4 + 0] = w.x; T[r][c4 + 1] = w.y;
    T[r][c4 + 2] = w.z; T[r][c4 + 3] = w.w;
    __syncthreads();
    half4 h = { (_Float16)T[c4 + 0][r], (_Float16)T[c4 + 1][r],
                (_Float16)T[c4 + 2][r], (_Float16)T[c4 + 3][r] };
    *(half4*)(Wt + (size_t)(n0 + r) * K + k0 + c4) = h;
}

// ---------------------------------------------------------------------------
// V section of qkv_h -> vt[bh][d][s]
// ---------------------------------------------------------------------------
__global__ __launch_bounds__(256)
void transpose_v(const _Float16* __restrict__ qkv, _Float16* __restrict__ vt)
{
    __shared__ _Float16 T[64][66];
    const int st = blockIdx.x, bh = blockIdx.y;
    const int b = bh >> 4, h = bh & 15;
    const int t = threadIdx.x;
    const int sr = t >> 2, dc = (t & 3) * 16;

    const _Float16* src = qkv + ((size_t)(b * S_LEN + st * 64 + sr)) * QKV_N
                              + 2 * EMB + h * HD + dc;
    half8 v0 = *(const half8*)(src);
    half8 v1 = *(const half8*)(src + 8);
#pragma unroll
    for (int j = 0; j < 8; ++j) { T[sr][dc + j] = v0[j]; T[sr][dc + 8 + j] = v1[j]; }
    __syncthreads();

    const int dr = t >> 2, sc = (t & 3) * 16;
    half8 o0, o1;
#pragma unroll
    for (int j = 0; j < 8; ++j) { o0[j] = T[sc + j][dr]; o1[j] = T[sc + 8 + j][dr]; }
    _Float16* dst = vt + (size_t)bh * HD * S_LEN + (size_t)dr * S_LEN + st * 64 + sc;
    *(half8*)(dst)     = o0;
    *(half8*)(dst + 8) = o1;
}

// ---------------------------------------------------------------------------
// m97-style f16 MFMA GEMM. Tile BM x 128 x 32, BM = MT*32.
// ---------------------------------------------------------------------------
template <int MT, int MINW, bool OUT_F16>
__global__ __launch_bounds__(256, MINW)
void hgemm_lds(const _Float16* __restrict__ X, const _Float16* __restrict__ Wt,
               const float* __restrict__ bias, void* __restrict__ Cout,
               int M, int N, int K)
{
    constexpr int BM = MT * 32;
    constexpr int CA = BM / 64;
    __shared__ _Float16 As[BM][32];
    __shared__ _Float16 Bs[128][32];

    const int tid  = threadIdx.x;
    const int wave = tid >> 6, lane = tid & 63;
    const int quad = lane >> 4, l15 = lane & 15;
    const int wm = (wave >> 1) * (MT * 16);
    const int wn = (wave & 1) * 64;
    const int m0 = blockIdx.y * BM, n0 = blockIdx.x * 128;

    const int lrow = lane >> 2;
    const int lcol = (lane & 3) * 8;

    const _Float16* xg[CA];
#pragma unroll
    for (int t = 0; t < CA; ++t)
        xg[t] = X + (size_t)(m0 + t * 64 + wave * 16 + lrow) * K + lcol;
    const _Float16* wg[2];
#pragma unroll
    for (int t = 0; t < 2; ++t)
        wg[t] = Wt + (size_t)(n0 + t * 64 + wave * 16 + lrow) * K + lcol;

    f32x4 acc[MT][4] = {};

    for (int k0 = 0; k0 < K; k0 += 32) {
#pragma unroll
        for (int t = 0; t < CA; ++t)
            stage16(xg[t] + k0, &As[t * 64 + wave * 16][0], lane);
#pragma unroll
        for (int t = 0; t < 2; ++t)
            stage16(wg[t] + k0, &Bs[t * 64 + wave * 16][0], lane);
        __syncthreads();

        half8 af[MT], bf[4];
#pragma unroll
        for (int mt = 0; mt < MT; ++mt)
            af[mt] = *(const half8*)&As[wm + mt * 16 + l15][quad * 8];
#pragma unroll
        for (int nt = 0; nt < 4; ++nt)
            bf[nt] = *(const half8*)&Bs[wn + nt * 16 + l15][quad * 8];
#pragma unroll
        for (int mt = 0; mt < MT; ++mt)
#pragma unroll
            for (int nt = 0; nt < 4; ++nt)
                acc[mt][nt] = __builtin_amdgcn_mfma_f32_16x16x32_f16(
                    af[mt], bf[nt], acc[mt][nt], 0, 0, 0);
        __syncthreads();
    }

#pragma unroll
    for (int nt = 0; nt < 4; ++nt) {
        const int c = n0 + wn + nt * 16 + l15;
        const float bv = bias[c];
#pragma unroll
        for (int mt = 0; mt < MT; ++mt)
#pragma unroll
            for (int reg = 0; reg < 4; ++reg) {
                const int r = m0 + wm + mt * 16 + quad * 4 + reg;
                const float v = acc[mt][nt][reg] + bv;
                if (OUT_F16)
                    ((_Float16*)Cout)[(size_t)r * N + c] = (_Float16)v;
                else
                    ((float*)Cout)[(size_t)r * N + c] = v;
            }
    }
}

// ---------------------------------------------------------------------------
// MFMA flash attention v4: S^T formulation, zero P round-trip.
// Grid 1024 (balanced decode), 4 waves, q-tile 64 (16/wave), k-tile 128.
// S^T = K.Q^T via 16x16x32 (C-layout: col=q, row=kseq). exp2-softmax with
// cross-quad-only shuffles. P^T C-regs feed PV directly as B-operands of
// 16x16x16 MFMAs (B[n=l15=q][k=quad*4+j=kseq]). O^T accumulates with d on
// quad*4+reg -> contiguous half4 stores.
// ---------------------------------------------------------------------------
__global__ __launch_bounds__(256, 4)
void attn_fa_mfma4(const _Float16* __restrict__ qkv,
                   const _Float16* __restrict__ vt,
                   _Float16* __restrict__ outh)
{
    __shared__ _Float16 Ks[128][72];      // [kseq][d]
    __shared__ _Float16 Vs[64][136];      // [d][kseq]

    const int n    = blockIdx.x;          // 0..1023
    const int half = n >> 9, idx = n & 511;
    const int bh   = idx >> 4, jj = idx & 15;
    const int qt   = half ? (31 - jj) : jj;
    const int b = bh >> 4, h = bh & 15;

    const int tid  = threadIdx.x;
    const int wave = tid >> 6, lane = tid & 63;
    const int quad = lane >> 4, l15 = lane & 15;
    const size_t row0 = (size_t)b * S_LEN;

    // Q fragments (B-operand: n=l15=q, k=quad*8+j=d), pre-scaled by log2(e)/16
    const _Float16 qscale = (_Float16)0.0901684400555602f;
    half8 qf[2];
    {
        const size_t qrow = row0 + qt * 64 + wave * 16 + l15;
        const _Float16* qp = qkv + qrow * QKV_N + h * HD + quad * 8;
#pragma unroll
        for (int c = 0; c < 2; ++c) {
            half8 q = *(const half8*)(qp + c * 32);
#pragma unroll
            for (int j = 0; j < 8; ++j) q[j] = q[j] * qscale;
            qf[c] = q;
        }
    }

    f32x4 o_acc[4] = {};            // O^T: d = dt*16 + quad*4+reg, q = l15
    float m_i = -1e30f, l_i = 0.0f; // per-lane (q = wave*16 + l15)

    const int ksr = tid >> 1, ksc = (tid & 1) * 32;
    const int vsr = tid >> 2, vsc = (tid & 3) * 32;
    const _Float16* vbase = vt + (size_t)bh * HD * S_LEN;

    const int ktN = (qt + 2) >> 1;
    for (int kt = 0; kt < ktN; ++kt) {
        __syncthreads();
        {
            const _Float16* ksrc = qkv + (row0 + kt * 128 + ksr) * QKV_N
                                       + EMB + h * HD + ksc;
            half8 k0 = *(const half8*)(ksrc);
            half8 k1 = *(const half8*)(ksrc + 8);
            half8 k2 = *(const half8*)(ksrc + 16);
            half8 k3 = *(const half8*)(ksrc + 24);
            *(half8*)&Ks[ksr][ksc]      = k0;
            *(half8*)&Ks[ksr][ksc + 8]  = k1;
            *(half8*)&Ks[ksr][ksc + 16] = k2;
            *(half8*)&Ks[ksr][ksc + 24] = k3;
            const _Float16* vsrc = vbase + (size_t)vsr * S_LEN + kt * 128 + vsc;
            half8 v0 = *(const half8*)(vsrc);
            half8 v1 = *(const half8*)(vsrc + 8);
            half8 v2 = *(const half8*)(vsrc + 16);
            half8 v3 = *(const half8*)(vsrc + 24);
            *(half8*)&Vs[vsr][vsc]      = v0;
            *(half8*)&Vs[vsr][vsc + 8]  = v1;
            *(half8*)&Vs[vsr][vsc + 16] = v2;
            *(half8*)&Vs[vsr][vsc + 24] = v3;
        }
        __syncthreads();

        // ---- S^T = K Q^T : 8 kseq-tiles x 2 d-chunks ----
        f32x4 st[8] = {};
#pragma unroll
        for (int c = 0; c < 2; ++c)
#pragma unroll
            for (int nt = 0; nt < 8; ++nt) {
                half8 kf = *(const half8*)&Ks[nt * 16 + l15][c * 32 + quad * 8];
                st[nt] = __builtin_amdgcn_mfma_f32_16x16x32_f16(kf, qf[c], st[nt], 0, 0, 0);
            }

        // ---- causal mask (last tile only): kseq > q ----
        if (kt == ktN - 1) {
            const int q = qt * 64 + wave * 16 + l15;
#pragma unroll
            for (int nt = 0; nt < 8; ++nt) {
                const int ks = kt * 128 + nt * 16 + quad * 4;
#pragma unroll
                for (int reg = 0; reg < 4; ++reg)
                    if (ks + reg > q) st[nt][reg] = -1e30f;
            }
        }

        // ---- online softmax, per-lane row state, cross-quad shuffles only ----
        float rm = fmaxf(fmaxf(st[0][0], st[0][1]), fmaxf(st[0][2], st[0][3]));
#pragma unroll
        for (int nt = 1; nt < 8; ++nt) {
            rm = fmaxf(rm, fmaxf(st[nt][0], st[nt][1]));
            rm = fmaxf(rm, fmaxf(st[nt][2], st[nt][3]));
        }
        rm = fmaxf(rm, __shfl_xor(rm, 16));
        rm = fmaxf(rm, __shfl_xor(rm, 32));
        const float mnew  = fmaxf(m_i, rm);
        const float alpha = __builtin_amdgcn_exp2f(m_i - mnew);
        float rs = 0.0f;
        half4 pf[8];
#pragma unroll
        for (int nt = 0; nt < 8; ++nt) {
            float p0 = __builtin_amdgcn_exp2f(st[nt][0] - mnew);
            float p1 = __builtin_amdgcn_exp2f(st[nt][1] - mnew);
            float p2 = __builtin_amdgcn_exp2f(st[nt][2] - mnew);
            float p3 = __builtin_amdgcn_exp2f(st[nt][3] - mnew);
            rs += (p0 + p1) + (p2 + p3);
            pf[nt] = half4{ (_Float16)p0, (_Float16)p1, (_Float16)p2, (_Float16)p3 };
        }
        rs += __shfl_xor(rs, 16);
        rs += __shfl_xor(rs, 32);
        l_i = l_i * alpha + rs;
        m_i = mnew;
#pragma unroll
        for (int dt = 0; dt < 4; ++dt)
#pragma unroll
            for (int reg = 0; reg < 4; ++reg) o_acc[dt][reg] *= alpha;

        // ---- O^T += V^T P^T  (P straight from registers) ----
#pragma unroll
        for (int nt = 0; nt < 8; ++nt)
#pragma unroll
            for (int dt = 0; dt < 4; ++dt) {
                half4 vf = *(const half4*)&Vs[dt * 16 + l15][nt * 16 + quad * 4];
                o_acc[dt] = __builtin_amdgcn_mfma_f32_16x16x16f16(vf, pf[nt], o_acc[dt], 0, 0, 0);
            }
    }

    // ---- normalize, write f16: lane q = l15, d = dt*16 + quad*4 + reg ----
    const float inv = 1.0f / l_i;
    const size_t r = row0 + qt * 64 + wave * 16 + l15;
#pragma unroll
    for (int dt = 0; dt < 4; ++dt) {
        half4 o = { (_Float16)(o_acc[dt][0] * inv), (_Float16)(o_acc[dt][1] * inv),
                    (_Float16)(o_acc[dt][2] * inv), (_Float16)(o_acc[dt][3] * inv) };
        *(half4*)(outh + r * EMB + h * HD + dt * 16 + quad * 4) = o;
    }
}

// ---------------------------------------------------------------------------
extern "C" void kernel_launch(void* const* d_in, const int* in_sizes, int n_in,
                              void* d_out, int out_size, void* d_ws, size_t ws_size,
                              hipStream_t stream)
{
    const float* hidden = (const float*)d_in[0];
    const float* w_attn = (const float*)d_in[1];
    const float* b_attn = (const float*)d_in[2];
    const float* w_proj = (const float*)d_in[3];
    const float* b_proj = (const float*)d_in[4];

    _Float16* hidden_h = (_Float16*)d_ws;                        // 4M
    _Float16* wattn_t  = hidden_h + (size_t)MROWS * EMB;         // 3M
    _Float16* wproj_t  = wattn_t + (size_t)EMB * QKV_N;          // 1M
    _Float16* qkv_h    = wproj_t + (size_t)EMB * EMB;            // 12M
    _Float16* attn_h   = qkv_h + (size_t)MROWS * QKV_N;          // 4M
    _Float16* vt       = attn_h + (size_t)MROWS * EMB;           // 4M

    cast_f32_f16<<<(MROWS * EMB) / 1024, 256, 0, stream>>>(hidden, hidden_h);
    transpose_cast<<<dim3(QKV_N / 32, EMB / 32), 256, 0, stream>>>(
        w_attn, wattn_t, EMB, QKV_N);
    transpose_cast<<<dim3(EMB / 32, EMB / 32), 256, 0, stream>>>(
        w_proj, wproj_t, EMB, EMB);

    hgemm_lds<4, 3, true><<<dim3(QKV_N / 128, MROWS / 128), 256, 0, stream>>>(
        hidden_h, wattn_t, b_attn, qkv_h, MROWS, QKV_N, EMB);

    transpose_v<<<dim3(S_LEN / 64, B_DIM * NH), 256, 0, stream>>>(qkv_h, vt);

    attn_fa_mfma4<<<dim3(1024), 256, 0, stream>>>(qkv_h, vt, attn_h);

    hgemm_lds<2, 4, false><<<dim3(EMB / 128, MROWS / 64), 256, 0, stream>>>(
        attn_h, wproj_t, b_proj, d_out, MROWS, EMB, EMB);
}

// Round 6
// 188.915 us; speedup vs baseline: 8.4374x; 1.0763x over previous
//
#include <hip/hip_runtime.h>
#include <cstddef>
#include <cstdint>

#define B_DIM   2
#define S_LEN   2048
#define EMB     1024
#define NH      16
#define HD      64
#define QKV_N   3072
#define MROWS   (B_DIM * S_LEN)

using half8  = __attribute__((ext_vector_type(8))) _Float16;
using half4  = __attribute__((ext_vector_type(4))) _Float16;
using f32x4  = __attribute__((ext_vector_type(4))) float;

#if defined(__has_builtin)
#if __has_builtin(__builtin_amdgcn_global_load_lds)
#define HAS_GLL 1
#endif
#endif

// One wave-call stages 1 KB: lane deposits 16 B at lds_base + lane*16.
__device__ __forceinline__ void stage16(const _Float16* g, _Float16* lds_base, int lane)
{
#ifdef HAS_GLL
    (void)lane;
    __builtin_amdgcn_global_load_lds(
        (const __attribute__((address_space(1))) unsigned int*)g,
        (__attribute__((address_space(3))) unsigned int*)lds_base, 16, 0, 0);
#else
    *(half8*)(lds_base + lane * 8) = *(const half8*)g;
#endif
}

// ---------------------------------------------------------------------------
// fp32 -> f16 elementwise cast
// ---------------------------------------------------------------------------
__global__ __launch_bounds__(256)
void cast_f32_f16(const float* __restrict__ src, _Float16* __restrict__ dst)
{
    int i = (blockIdx.x * 256 + threadIdx.x) * 4;
    float4 v = *(const float4*)(src + i);
    half4 h = { (_Float16)v.x, (_Float16)v.y, (_Float16)v.z, (_Float16)v.w };
    *(half4*)(dst + i) = h;
}

// ---------------------------------------------------------------------------
// W [K][N] fp32  ->  Wt [N][K] f16
// ---------------------------------------------------------------------------
__global__ __launch_bounds__(256)
void transpose_cast(const float* __restrict__ W, _Float16* __restrict__ Wt,
                    int K, int N)
{
    __shared__ float T[32][33];
    const int n0 = blockIdx.x * 32, k0 = blockIdx.y * 32;
    const int t = threadIdx.x;
    const int r = t >> 3, c4 = (t & 7) * 4;
    float4 w = *(const float4*)(W + (size_t)(k0 + r) * N + n0 + c4);
    T[r][c4 + 0] = w.x; T[r][c4 + 1] = w.y;
    T[r][c4 + 2] = w.z; T[r][c4 + 3] = w.w;
    __syncthreads();
    half4 h = { (_Float16)T[c4 + 0][r], (_Float16)T[c4 + 1][r],
                (_Float16)T[c4 + 2][r], (_Float16)T[c4 + 3][r] };
    *(half4*)(Wt + (size_t)(n0 + r) * K + k0 + c4) = h;
}

// ---------------------------------------------------------------------------
// V section of qkv_h -> vt[bh][d][s]
// ---------------------------------------------------------------------------
__global__ __launch_bounds__(256)
void transpose_v(const _Float16* __restrict__ qkv, _Float16* __restrict__ vt)
{
    __shared__ _Float16 T[64][66];
    const int st = blockIdx.x, bh = blockIdx.y;
    const int b = bh >> 4, h = bh & 15;
    const int t = threadIdx.x;
    const int sr = t >> 2, dc = (t & 3) * 16;

    const _Float16* src = qkv + ((size_t)(b * S_LEN + st * 64 + sr)) * QKV_N
                              + 2 * EMB + h * HD + dc;
    half8 v0 = *(const half8*)(src);
    half8 v1 = *(const half8*)(src + 8);
#pragma unroll
    for (int j = 0; j < 8; ++j) { T[sr][dc + j] = v0[j]; T[sr][dc + 8 + j] = v1[j]; }
    __syncthreads();

    const int dr = t >> 2, sc = (t & 3) * 16;
    half8 o0, o1;
#pragma unroll
    for (int j = 0; j < 8; ++j) { o0[j] = T[sc + j][dr]; o1[j] = T[sc + 8 + j][dr]; }
    _Float16* dst = vt + (size_t)bh * HD * S_LEN + (size_t)dr * S_LEN + st * 64 + sc;
    *(half8*)(dst)     = o0;
    *(half8*)(dst + 8) = o1;
}

// ---------------------------------------------------------------------------
// f16 MFMA GEMM, BK=64, GLL staging, XOR-swizzled LDS columns.
// Tile BM x 128 x 64, BM = MT*32. Logical col-group g (16B units) of row r
// lives at physical group g ^ (r&7); staging bakes the swizzle into the
// global source column, so GLL's lane-contiguous deposit needs no change.
// ---------------------------------------------------------------------------
template <int MT, int MINW, bool OUT_F16>
__global__ __launch_bounds__(256, MINW)
void hgemm_lds(const _Float16* __restrict__ X, const _Float16* __restrict__ Wt,
               const float* __restrict__ bias, void* __restrict__ Cout,
               int M, int N, int K)
{
    constexpr int BM = MT * 32;
    constexpr int ACALLS = BM / 32;        // A-stage GLL calls per wave
    __shared__ _Float16 As[BM][64];
    __shared__ _Float16 Bs[128][64];

    const int tid  = threadIdx.x;
    const int wave = tid >> 6, lane = tid & 63;
    const int quad = lane >> 4, l15 = lane & 15;
    const int wm = (wave >> 1) * (MT * 16);
    const int wn = (wave & 1) * 64;
    const int m0 = blockIdx.y * BM, n0 = blockIdx.x * 128;

    const int srow = lane >> 3;                  // 0..7 row within GLL call
    const int scol = ((lane & 7) ^ srow) * 8;    // swizzled logical col

    const _Float16* xg[ACALLS];
#pragma unroll
    for (int c = 0; c < ACALLS; ++c)
        xg[c] = X + (size_t)(m0 + wave * (BM / 4) + c * 8 + srow) * K + scol;
    const _Float16* wg[4];
#pragma unroll
    for (int c = 0; c < 4; ++c)
        wg[c] = Wt + (size_t)(n0 + wave * 32 + c * 8 + srow) * K + scol;

    f32x4 acc[MT][4] = {};
    const int sx = l15 & 7;                      // fragment-read swizzle key

    for (int k0 = 0; k0 < K; k0 += 64) {
#pragma unroll
        for (int c = 0; c < ACALLS; ++c)
            stage16(xg[c] + k0, &As[wave * (BM / 4) + c * 8][0], lane);
#pragma unroll
        for (int c = 0; c < 4; ++c)
            stage16(wg[c] + k0, &Bs[wave * 32 + c * 8][0], lane);
        __syncthreads();

#pragma unroll
        for (int cc = 0; cc < 2; ++cc) {
            half8 af[MT], bf[4];
#pragma unroll
            for (int mt = 0; mt < MT; ++mt)
                af[mt] = *(const half8*)&As[wm + mt * 16 + l15][(((cc * 4 + quad) ^ sx)) * 8];
#pragma unroll
            for (int nt = 0; nt < 4; ++nt)
                bf[nt] = *(const half8*)&Bs[wn + nt * 16 + l15][(((cc * 4 + quad) ^ sx)) * 8];
#pragma unroll
            for (int mt = 0; mt < MT; ++mt)
#pragma unroll
                for (int nt = 0; nt < 4; ++nt)
                    acc[mt][nt] = __builtin_amdgcn_mfma_f32_16x16x32_f16(
                        af[mt], bf[nt], acc[mt][nt], 0, 0, 0);
        }
        __syncthreads();
    }

#pragma unroll
    for (int nt = 0; nt < 4; ++nt) {
        const int c = n0 + wn + nt * 16 + l15;
        const float bv = bias[c];
#pragma unroll
        for (int mt = 0; mt < MT; ++mt)
#pragma unroll
            for (int reg = 0; reg < 4; ++reg) {
                const int r = m0 + wm + mt * 16 + quad * 4 + reg;
                const float v = acc[mt][nt][reg] + bv;
                if (OUT_F16)
                    ((_Float16*)Cout)[(size_t)r * N + c] = (_Float16)v;
                else
                    ((float*)Cout)[(size_t)r * N + c] = v;
            }
    }
}

// ---------------------------------------------------------------------------
// MFMA flash attention v5: S^T formulation + GLL staging + swizzled LDS +
// skip-rescale. Grid 1024 (balanced decode), 4 waves, q-tile 64, k-tile 128.
// ---------------------------------------------------------------------------
__global__ __launch_bounds__(256, 4)
void attn_fa_mfma5(const _Float16* __restrict__ qkv,
                   const _Float16* __restrict__ vt,
                   _Float16* __restrict__ outh)
{
    __shared__ _Float16 Ks[128][64];      // [kseq][d], col-group swizzled by kseq&7
    __shared__ _Float16 Vs[64][128];      // [d][kseq], col-group swizzled by d&15

    const int n    = blockIdx.x;
    const int half = n >> 9, idx = n & 511;
    const int bh   = idx >> 4, jj = idx & 15;
    const int qt   = half ? (31 - jj) : jj;
    const int b = bh >> 4, h = bh & 15;

    const int tid  = threadIdx.x;
    const int wave = tid >> 6, lane = tid & 63;
    const int quad = lane >> 4, l15 = lane & 15;
    const size_t row0 = (size_t)b * S_LEN;

    // Q fragments (B-operand: n=l15=q, k=quad*8+j=d), pre-scaled by log2(e)/16
    const _Float16 qscale = (_Float16)0.0901684400555602f;
    half8 qf[2];
    {
        const size_t qrow = row0 + qt * 64 + wave * 16 + l15;
        const _Float16* qp = qkv + qrow * QKV_N + h * HD + quad * 8;
#pragma unroll
        for (int c = 0; c < 2; ++c) {
            half8 q = *(const half8*)(qp + c * 32);
#pragma unroll
            for (int j = 0; j < 8; ++j) q[j] = q[j] * qscale;
            qf[c] = q;
        }
    }

    f32x4 o_acc[4] = {};
    float m_i = -1e30f, l_i = 0.0f;

    // staging maps
    const int ksrow = lane >> 3;                         // K: 8 rows/call
    const int kscol = ((lane & 7) ^ ksrow) * 8;          // swizzled d-col
    const int vsrow = lane >> 4;                         // V: 4 rows/call
    const _Float16* vbase = vt + (size_t)bh * HD * S_LEN;
    const int sxk = l15 & 7;                             // kf read swizzle key

    const int ktN = (qt + 2) >> 1;
    for (int kt = 0; kt < ktN; ++kt) {
        __syncthreads();
        {
            const _Float16* kbase = qkv + (row0 + kt * 128) * QKV_N + EMB + h * HD;
#pragma unroll
            for (int c = 0; c < 4; ++c) {
                const int r0 = wave * 32 + c * 8;
                stage16(kbase + (size_t)(r0 + ksrow) * QKV_N + kscol,
                        &Ks[r0][0], lane);
            }
#pragma unroll
            for (int c = 0; c < 4; ++c) {
                const int r0 = wave * 16 + c * 4;        // d-row base
                const int sgv = ((lane & 15) ^ (c * 4 + vsrow)) * 8;
                stage16(vbase + (size_t)(r0 + vsrow) * S_LEN + kt * 128 + sgv,
                        &Vs[r0][0], lane);
            }
        }
        __syncthreads();

        // ---- S^T = K Q^T : 8 kseq-tiles x 2 d-chunks ----
        f32x4 st[8] = {};
#pragma unroll
        for (int c = 0; c < 2; ++c)
#pragma unroll
            for (int nt = 0; nt < 8; ++nt) {
                half8 kf = *(const half8*)&Ks[nt * 16 + l15][((c * 4 + quad) ^ sxk) * 8];
                st[nt] = __builtin_amdgcn_mfma_f32_16x16x32_f16(kf, qf[c], st[nt], 0, 0, 0);
            }

        // ---- causal mask (last tile only): kseq > q ----
        if (kt == ktN - 1) {
            const int q = qt * 64 + wave * 16 + l15;
#pragma unroll
            for (int nt = 0; nt < 8; ++nt) {
                const int ks = kt * 128 + nt * 16 + quad * 4;
#pragma unroll
                for (int reg = 0; reg < 4; ++reg)
                    if (ks + reg > q) st[nt][reg] = -1e30f;
            }
        }

        // ---- online softmax (per-lane row state, cross-quad shuffles) ----
        float rm = fmaxf(fmaxf(st[0][0], st[0][1]), fmaxf(st[0][2], st[0][3]));
#pragma unroll
        for (int nt = 1; nt < 8; ++nt) {
            rm = fmaxf(rm, fmaxf(st[nt][0], st[nt][1]));
            rm = fmaxf(rm, fmaxf(st[nt][2], st[nt][3]));
        }
        rm = fmaxf(rm, __shfl_xor(rm, 16));
        rm = fmaxf(rm, __shfl_xor(rm, 32));
        const float mnew = fmaxf(m_i, rm);

        if (__ballot(mnew > m_i)) {          // wave-uniform: rescale only if needed
            const float alpha = __builtin_amdgcn_exp2f(m_i - mnew);
            l_i *= alpha;
#pragma unroll
            for (int dt = 0; dt < 4; ++dt)
#pragma unroll
                for (int reg = 0; reg < 4; ++reg) o_acc[dt][reg] *= alpha;
        }
        m_i = mnew;

        float rs = 0.0f;
        half4 pf[8];
#pragma unroll
        for (int nt = 0; nt < 8; ++nt) {
            float p0 = __builtin_amdgcn_exp2f(st[nt][0] - mnew);
            float p1 = __builtin_amdgcn_exp2f(st[nt][1] - mnew);
            float p2 = __builtin_amdgcn_exp2f(st[nt][2] - mnew);
            float p3 = __builtin_amdgcn_exp2f(st[nt][3] - mnew);
            rs += (p0 + p1) + (p2 + p3);
            pf[nt] = half4{ (_Float16)p0, (_Float16)p1, (_Float16)p2, (_Float16)p3 };
        }
        rs += __shfl_xor(rs, 16);
        rs += __shfl_xor(rs, 32);
        l_i += rs;

        // ---- O^T += V^T P^T  (P straight from registers) ----
#pragma unroll
        for (int nt = 0; nt < 8; ++nt)
#pragma unroll
            for (int dt = 0; dt < 4; ++dt) {
                const int pg = ((2 * nt + (quad >> 1)) ^ l15) * 8 + (quad & 1) * 4;
                half4 vf = *(const half4*)&Vs[dt * 16 + l15][pg];
                o_acc[dt] = __builtin_amdgcn_mfma_f32_16x16x16f16(vf, pf[nt], o_acc[dt], 0, 0, 0);
            }
    }

    // ---- normalize, write f16: q = l15 row, d = dt*16 + quad*4 + reg ----
    const float inv = 1.0f / l_i;
    const size_t r = row0 + qt * 64 + wave * 16 + l15;
#pragma unroll
    for (int dt = 0; dt < 4; ++dt) {
        half4 o = { (_Float16)(o_acc[dt][0] * inv), (_Float16)(o_acc[dt][1] * inv),
                    (_Float16)(o_acc[dt][2] * inv), (_Float16)(o_acc[dt][3] * inv) };
        *(half4*)(outh + r * EMB + h * HD + dt * 16 + quad * 4) = o;
    }
}

// ---------------------------------------------------------------------------
extern "C" void kernel_launch(void* const* d_in, const int* in_sizes, int n_in,
                              void* d_out, int out_size, void* d_ws, size_t ws_size,
                              hipStream_t stream)
{
    const float* hidden = (const float*)d_in[0];
    const float* w_attn = (const float*)d_in[1];
    const float* b_attn = (const float*)d_in[2];
    const float* w_proj = (const float*)d_in[3];
    const float* b_proj = (const float*)d_in[4];

    _Float16* hidden_h = (_Float16*)d_ws;                        // 4M
    _Float16* wattn_t  = hidden_h + (size_t)MROWS * EMB;         // 3M
    _Float16* wproj_t  = wattn_t + (size_t)EMB * QKV_N;          // 1M
    _Float16* qkv_h    = wproj_t + (size_t)EMB * EMB;            // 12M
    _Float16* attn_h   = qkv_h + (size_t)MROWS * QKV_N;          // 4M
    _Float16* vt       = attn_h + (size_t)MROWS * EMB;           // 4M

    cast_f32_f16<<<(MROWS * EMB) / 1024, 256, 0, stream>>>(hidden, hidden_h);
    transpose_cast<<<dim3(QKV_N / 32, EMB / 32), 256, 0, stream>>>(
        w_attn, wattn_t, EMB, QKV_N);
    transpose_cast<<<dim3(EMB / 32, EMB / 32), 256, 0, stream>>>(
        w_proj, wproj_t, EMB, EMB);

    hgemm_lds<4, 3, true><<<dim3(QKV_N / 128, MROWS / 128), 256, 0, stream>>>(
        hidden_h, wattn_t, b_attn, qkv_h, MROWS, QKV_N, EMB);

    transpose_v<<<dim3(S_LEN / 64, B_DIM * NH), 256, 0, stream>>>(qkv_h, vt);

    attn_fa_mfma5<<<dim3(1024), 256, 0, stream>>>(qkv_h, vt, attn_h);

    hgemm_lds<2, 4, false><<<dim3(EMB / 128, MROWS / 64), 256, 0, stream>>>(
        attn_h, wproj_t, b_proj, d_out, MROWS, EMB, EMB);
}

// Round 7
// 183.742 us; speedup vs baseline: 8.6750x; 1.0282x over previous
//
#include <hip/hip_runtime.h>
#include <cstddef>
#include <cstdint>

#define B_DIM   2
#define S_LEN   2048
#define EMB     1024
#define NH      16
#define HD      64
#define QKV_N   3072
#define MROWS   (B_DIM * S_LEN)

using half8  = __attribute__((ext_vector_type(8))) _Float16;
using half4  = __attribute__((ext_vector_type(4))) _Float16;
using f32x4  = __attribute__((ext_vector_type(4))) float;

#if defined(__has_builtin)
#if __has_builtin(__builtin_amdgcn_global_load_lds)
#define HAS_GLL 1
#endif
#endif

// One wave-call stages 1 KB: lane deposits 16 B at lds_base + lane*16.
__device__ __forceinline__ void stage16(const _Float16* g, _Float16* lds_base, int lane)
{
#ifdef HAS_GLL
    (void)lane;
    __builtin_amdgcn_global_load_lds(
        (const __attribute__((address_space(1))) unsigned int*)g,
        (__attribute__((address_space(3))) unsigned int*)lds_base, 16, 0, 0);
#else
    *(half8*)(lds_base + lane * 8) = *(const half8*)g;
#endif
}

// ---------------------------------------------------------------------------
// Merged prep: [0,4096) cast hidden; [4096,7168) transpose w_attn;
// [7168,8192) transpose w_proj. All branches block-uniform.
// ---------------------------------------------------------------------------
__global__ __launch_bounds__(256)
void prep_all(const float* __restrict__ hidden, const float* __restrict__ w_attn,
              const float* __restrict__ w_proj, _Float16* __restrict__ hidden_h,
              _Float16* __restrict__ wattn_t, _Float16* __restrict__ wproj_t)
{
    const int bid = blockIdx.x, t = threadIdx.x;
    if (bid < 4096) {
        int i = bid * 1024 + t * 4;
        float4 v = *(const float4*)(hidden + i);
        half4 h = { (_Float16)v.x, (_Float16)v.y, (_Float16)v.z, (_Float16)v.w };
        *(half4*)(hidden_h + i) = h;
        return;
    }
    __shared__ float T[32][33];
    const float* W; _Float16* Wt; int N, bx, by;
    if (bid < 7168) {
        int t2 = bid - 4096; bx = t2 % 96; by = t2 / 96; W = w_attn; Wt = wattn_t; N = QKV_N;
    } else {
        int t3 = bid - 7168; bx = t3 & 31; by = t3 >> 5; W = w_proj; Wt = wproj_t; N = EMB;
    }
    const int n0 = bx * 32, k0 = by * 32;
    const int r = t >> 3, c4 = (t & 7) * 4;
    float4 w = *(const float4*)(W + (size_t)(k0 + r) * N + n0 + c4);
    T[r][c4 + 0] = w.x; T[r][c4 + 1] = w.y;
    T[r][c4 + 2] = w.z; T[r][c4 + 3] = w.w;
    __syncthreads();
    half4 h = { (_Float16)T[c4 + 0][r], (_Float16)T[c4 + 1][r],
                (_Float16)T[c4 + 2][r], (_Float16)T[c4 + 3][r] };
    *(half4*)(Wt + (size_t)(n0 + r) * EMB + k0 + c4) = h;
}

// ---------------------------------------------------------------------------
// f16 MFMA GEMM, BK=64, GLL staging, XOR-swizzled LDS columns.
// FUSE_VT: blocks with n0 >= 2*EMB write V transposed into vt[bh][d][s]
// instead of Cout (QKV fusion).
// ---------------------------------------------------------------------------
template <int MT, int MINW, bool OUT_F16, bool FUSE_VT>
__global__ __launch_bounds__(256, MINW)
void hgemm_lds(const _Float16* __restrict__ X, const _Float16* __restrict__ Wt,
               const float* __restrict__ bias, void* __restrict__ Cout,
               _Float16* __restrict__ vt, int M, int N, int K)
{
    constexpr int BM = MT * 32;
    constexpr int ACALLS = BM / 32;
    __shared__ _Float16 As[BM][64];
    __shared__ _Float16 Bs[128][64];

    const int tid  = threadIdx.x;
    const int wave = tid >> 6, lane = tid & 63;
    const int quad = lane >> 4, l15 = lane & 15;
    const int wm = (wave >> 1) * (MT * 16);
    const int wn = (wave & 1) * 64;
    const int m0 = blockIdx.y * BM, n0 = blockIdx.x * 128;

    const int srow = lane >> 3;
    const int scol = ((lane & 7) ^ srow) * 8;

    const _Float16* xg[ACALLS];
#pragma unroll
    for (int c = 0; c < ACALLS; ++c)
        xg[c] = X + (size_t)(m0 + wave * (BM / 4) + c * 8 + srow) * K + scol;
    const _Float16* wg[4];
#pragma unroll
    for (int c = 0; c < 4; ++c)
        wg[c] = Wt + (size_t)(n0 + wave * 32 + c * 8 + srow) * K + scol;

    f32x4 acc[MT][4] = {};
    const int sx = l15 & 7;

    for (int k0 = 0; k0 < K; k0 += 64) {
#pragma unroll
        for (int c = 0; c < ACALLS; ++c)
            stage16(xg[c] + k0, &As[wave * (BM / 4) + c * 8][0], lane);
#pragma unroll
        for (int c = 0; c < 4; ++c)
            stage16(wg[c] + k0, &Bs[wave * 32 + c * 8][0], lane);
        __syncthreads();

#pragma unroll
        for (int cc = 0; cc < 2; ++cc) {
            half8 af[MT], bf[4];
#pragma unroll
            for (int mt = 0; mt < MT; ++mt)
                af[mt] = *(const half8*)&As[wm + mt * 16 + l15][(((cc * 4 + quad) ^ sx)) * 8];
#pragma unroll
            for (int nt = 0; nt < 4; ++nt)
                bf[nt] = *(const half8*)&Bs[wn + nt * 16 + l15][(((cc * 4 + quad) ^ sx)) * 8];
#pragma unroll
            for (int mt = 0; mt < MT; ++mt)
#pragma unroll
                for (int nt = 0; nt < 4; ++nt)
                    acc[mt][nt] = __builtin_amdgcn_mfma_f32_16x16x32_f16(
                        af[mt], bf[nt], acc[mt][nt], 0, 0, 0);
        }
        __syncthreads();
    }

    if (FUSE_VT && n0 >= 2 * EMB) {
        // V region: write transposed into vt[bh][d][s] (s = seq, 4 consecutive)
#pragma unroll
        for (int nt = 0; nt < 4; ++nt) {
            const int c  = n0 + wn + nt * 16 + l15;
            const float bv = bias[c];
            const int vcol = c - 2 * EMB;
            const int hh = vcol >> 6, dd = vcol & 63;
#pragma unroll
            for (int mt = 0; mt < MT; ++mt) {
                const int r = m0 + wm + mt * 16 + quad * 4;
                const int bb = r >> 11, ss = r & 2047;
                half4 o = { (_Float16)(acc[mt][nt][0] + bv), (_Float16)(acc[mt][nt][1] + bv),
                            (_Float16)(acc[mt][nt][2] + bv), (_Float16)(acc[mt][nt][3] + bv) };
                *(half4*)(vt + ((size_t)(bb * NH + hh) * HD + dd) * S_LEN + ss) = o;
            }
        }
        return;
    }

#pragma unroll
    for (int nt = 0; nt < 4; ++nt) {
        const int c = n0 + wn + nt * 16 + l15;
        const float bv = bias[c];
#pragma unroll
        for (int mt = 0; mt < MT; ++mt)
#pragma unroll
            for (int reg = 0; reg < 4; ++reg) {
                const int r = m0 + wm + mt * 16 + quad * 4 + reg;
                const float v = acc[mt][nt][reg] + bv;
                if (OUT_F16)
                    ((_Float16*)Cout)[(size_t)r * N + c] = (_Float16)v;
                else
                    ((float*)Cout)[(size_t)r * N + c] = v;
            }
    }
}

// ---------------------------------------------------------------------------
// MFMA flash attention v6: v5 + XCD-local block decode.
// xcd = n&7 -> 4 bh per XCD; all 32 q-blocks of a bh stay on one XCD so its
// K/V (512 KB) lives in that XCD's L2. Per-CU qt set {j0, j0+8, 31-j0, 23-j0}
// keeps work uniform (sum qt+2 = 70 for all j0).
// ---------------------------------------------------------------------------
__global__ __launch_bounds__(256, 4)
void attn_fa_mfma6(const _Float16* __restrict__ qkv,
                   const _Float16* __restrict__ vt,
                   _Float16* __restrict__ outh)
{
    __shared__ _Float16 Ks[128][64];
    __shared__ _Float16 Vs[64][128];

    const int n   = blockIdx.x;
    const int xcd = n & 7, g = (n >> 3) & 3, j = n >> 5;
    const int bh  = xcd * 4 + g;
    const int qt  = (j < 16) ? j : (47 - j);
    const int b = bh >> 4, h = bh & 15;

    const int tid  = threadIdx.x;
    const int wave = tid >> 6, lane = tid & 63;
    const int quad = lane >> 4, l15 = lane & 15;
    const size_t row0 = (size_t)b * S_LEN;

    const _Float16 qscale = (_Float16)0.0901684400555602f;
    half8 qf[2];
    {
        const size_t qrow = row0 + qt * 64 + wave * 16 + l15;
        const _Float16* qp = qkv + qrow * QKV_N + h * HD + quad * 8;
#pragma unroll
        for (int c = 0; c < 2; ++c) {
            half8 q = *(const half8*)(qp + c * 32);
#pragma unroll
            for (int j2 = 0; j2 < 8; ++j2) q[j2] = q[j2] * qscale;
            qf[c] = q;
        }
    }

    f32x4 o_acc[4] = {};
    float m_i = -1e30f, l_i = 0.0f;

    const int ksrow = lane >> 3;
    const int kscol = ((lane & 7) ^ ksrow) * 8;
    const int vsrow = lane >> 4;
    const _Float16* vbase = vt + (size_t)bh * HD * S_LEN;
    const int sxk = l15 & 7;

    const int ktN = (qt + 2) >> 1;
    for (int kt = 0; kt < ktN; ++kt) {
        __syncthreads();
        {
            const _Float16* kbase = qkv + (row0 + kt * 128) * QKV_N + EMB + h * HD;
#pragma unroll
            for (int c = 0; c < 4; ++c) {
                const int r0 = wave * 32 + c * 8;
                stage16(kbase + (size_t)(r0 + ksrow) * QKV_N + kscol,
                        &Ks[r0][0], lane);
            }
#pragma unroll
            for (int c = 0; c < 4; ++c) {
                const int r0 = wave * 16 + c * 4;
                const int sgv = ((lane & 15) ^ (c * 4 + vsrow)) * 8;
                stage16(vbase + (size_t)(r0 + vsrow) * S_LEN + kt * 128 + sgv,
                        &Vs[r0][0], lane);
            }
        }
        __syncthreads();

        // ---- S^T = K Q^T ----
        f32x4 st[8] = {};
#pragma unroll
        for (int c = 0; c < 2; ++c)
#pragma unroll
            for (int nt = 0; nt < 8; ++nt) {
                half8 kf = *(const half8*)&Ks[nt * 16 + l15][((c * 4 + quad) ^ sxk) * 8];
                st[nt] = __builtin_amdgcn_mfma_f32_16x16x32_f16(kf, qf[c], st[nt], 0, 0, 0);
            }

        if (kt == ktN - 1) {
            const int q = qt * 64 + wave * 16 + l15;
#pragma unroll
            for (int nt = 0; nt < 8; ++nt) {
                const int ks = kt * 128 + nt * 16 + quad * 4;
#pragma unroll
                for (int reg = 0; reg < 4; ++reg)
                    if (ks + reg > q) st[nt][reg] = -1e30f;
            }
        }

        // ---- online softmax ----
        float rm = fmaxf(fmaxf(st[0][0], st[0][1]), fmaxf(st[0][2], st[0][3]));
#pragma unroll
        for (int nt = 1; nt < 8; ++nt) {
            rm = fmaxf(rm, fmaxf(st[nt][0], st[nt][1]));
            rm = fmaxf(rm, fmaxf(st[nt][2], st[nt][3]));
        }
        rm = fmaxf(rm, __shfl_xor(rm, 16));
        rm = fmaxf(rm, __shfl_xor(rm, 32));
        const float mnew = fmaxf(m_i, rm);

        if (__ballot(mnew > m_i)) {
            const float alpha = __builtin_amdgcn_exp2f(m_i - mnew);
            l_i *= alpha;
#pragma unroll
            for (int dt = 0; dt < 4; ++dt)
#pragma unroll
                for (int reg = 0; reg < 4; ++reg) o_acc[dt][reg] *= alpha;
        }
        m_i = mnew;

        float rs = 0.0f;
        half4 pf[8];
#pragma unroll
        for (int nt = 0; nt < 8; ++nt) {
            float p0 = __builtin_amdgcn_exp2f(st[nt][0] - mnew);
            float p1 = __builtin_amdgcn_exp2f(st[nt][1] - mnew);
            float p2 = __builtin_amdgcn_exp2f(st[nt][2] - mnew);
            float p3 = __builtin_amdgcn_exp2f(st[nt][3] - mnew);
            rs += (p0 + p1) + (p2 + p3);
            pf[nt] = half4{ (_Float16)p0, (_Float16)p1, (_Float16)p2, (_Float16)p3 };
        }
        rs += __shfl_xor(rs, 16);
        rs += __shfl_xor(rs, 32);
        l_i += rs;

        // ---- O^T += V^T P^T ----
#pragma unroll
        for (int nt = 0; nt < 8; ++nt)
#pragma unroll
            for (int dt = 0; dt < 4; ++dt) {
                const int pg = ((2 * nt + (quad >> 1)) ^ l15) * 8 + (quad & 1) * 4;
                half4 vf = *(const half4*)&Vs[dt * 16 + l15][pg];
                o_acc[dt] = __builtin_amdgcn_mfma_f32_16x16x16f16(vf, pf[nt], o_acc[dt], 0, 0, 0);
            }
    }

    const float inv = 1.0f / l_i;
    const size_t r = row0 + qt * 64 + wave * 16 + l15;
#pragma unroll
    for (int dt = 0; dt < 4; ++dt) {
        half4 o = { (_Float16)(o_acc[dt][0] * inv), (_Float16)(o_acc[dt][1] * inv),
                    (_Float16)(o_acc[dt][2] * inv), (_Float16)(o_acc[dt][3] * inv) };
        *(half4*)(outh + r * EMB + h * HD + dt * 16 + quad * 4) = o;
    }
}

// ---------------------------------------------------------------------------
extern "C" void kernel_launch(void* const* d_in, const int* in_sizes, int n_in,
                              void* d_out, int out_size, void* d_ws, size_t ws_size,
                              hipStream_t stream)
{
    const float* hidden = (const float*)d_in[0];
    const float* w_attn = (const float*)d_in[1];
    const float* b_attn = (const float*)d_in[2];
    const float* w_proj = (const float*)d_in[3];
    const float* b_proj = (const float*)d_in[4];

    _Float16* hidden_h = (_Float16*)d_ws;                        // 4M
    _Float16* wattn_t  = hidden_h + (size_t)MROWS * EMB;         // 3M
    _Float16* wproj_t  = wattn_t + (size_t)EMB * QKV_N;          // 1M
    _Float16* qkv_h    = wproj_t + (size_t)EMB * EMB;            // 12M
    _Float16* attn_h   = qkv_h + (size_t)MROWS * QKV_N;          // 4M
    _Float16* vt       = attn_h + (size_t)MROWS * EMB;           // 4M

    prep_all<<<8192, 256, 0, stream>>>(hidden, w_attn, w_proj,
                                       hidden_h, wattn_t, wproj_t);

    hgemm_lds<4, 3, true, true><<<dim3(QKV_N / 128, MROWS / 128), 256, 0, stream>>>(
        hidden_h, wattn_t, b_attn, qkv_h, vt, MROWS, QKV_N, EMB);

    attn_fa_mfma6<<<dim3(1024), 256, 0, stream>>>(qkv_h, vt, attn_h);

    hgemm_lds<2, 4, false, false><<<dim3(EMB / 128, MROWS / 64), 256, 0, stream>>>(
        attn_h, wproj_t, b_proj, d_out, nullptr, MROWS, EMB, EMB);
}

// Round 8
// 172.683 us; speedup vs baseline: 9.2306x; 1.0640x over previous
//
#include <hip/hip_runtime.h>
#include <cstddef>
#include <cstdint>

#define B_DIM   2
#define S_LEN   2048
#define EMB     1024
#define NH      16
#define HD      64
#define QKV_N   3072
#define MROWS   (B_DIM * S_LEN)

using half8  = __attribute__((ext_vector_type(8))) _Float16;
using half4  = __attribute__((ext_vector_type(4))) _Float16;
using f32x4  = __attribute__((ext_vector_type(4))) float;

#if defined(__has_builtin)
#if __has_builtin(__builtin_amdgcn_global_load_lds)
#define HAS_GLL 1
#endif
#endif

__device__ __forceinline__ void stage16(const _Float16* g, _Float16* lds_base, int lane)
{
#ifdef HAS_GLL
    (void)lane;
    __builtin_amdgcn_global_load_lds(
        (const __attribute__((address_space(1))) unsigned int*)g,
        (__attribute__((address_space(3))) unsigned int*)lds_base, 16, 0, 0);
#else
    *(half8*)(lds_base + lane * 8) = *(const half8*)g;
#endif
}

// ---------------------------------------------------------------------------
// Merged prep: [0,4096) cast hidden; [4096,7168) transpose w_attn;
// [7168,8192) transpose w_proj.
// ---------------------------------------------------------------------------
__global__ __launch_bounds__(256)
void prep_all(const float* __restrict__ hidden, const float* __restrict__ w_attn,
              const float* __restrict__ w_proj, _Float16* __restrict__ hidden_h,
              _Float16* __restrict__ wattn_t, _Float16* __restrict__ wproj_t)
{
    const int bid = blockIdx.x, t = threadIdx.x;
    if (bid < 4096) {
        int i = bid * 1024 + t * 4;
        float4 v = *(const float4*)(hidden + i);
        half4 h = { (_Float16)v.x, (_Float16)v.y, (_Float16)v.z, (_Float16)v.w };
        *(half4*)(hidden_h + i) = h;
        return;
    }
    __shared__ float T[32][33];
    const float* W; _Float16* Wt; int N, bx, by;
    if (bid < 7168) {
        int t2 = bid - 4096; bx = t2 % 96; by = t2 / 96; W = w_attn; Wt = wattn_t; N = QKV_N;
    } else {
        int t3 = bid - 7168; bx = t3 & 31; by = t3 >> 5; W = w_proj; Wt = wproj_t; N = EMB;
    }
    const int n0 = bx * 32, k0 = by * 32;
    const int r = t >> 3, c4 = (t & 7) * 4;
    float4 w = *(const float4*)(W + (size_t)(k0 + r) * N + n0 + c4);
    T[r][c4 + 0] = w.x; T[r][c4 + 1] = w.y;
    T[r][c4 + 2] = w.z; T[r][c4 + 3] = w.w;
    __syncthreads();
    half4 h = { (_Float16)T[c4 + 0][r], (_Float16)T[c4 + 1][r],
                (_Float16)T[c4 + 2][r], (_Float16)T[c4 + 3][r] };
    *(half4*)(Wt + (size_t)(n0 + r) * EMB + k0 + c4) = h;
}

// ---------------------------------------------------------------------------
// f16 MFMA GEMM, BK=64, GLL staging, XOR-swizzled LDS columns.
// FUSE_VT: blocks with n0 >= 2*EMB write V transposed into vt[bh][d][s].
// ---------------------------------------------------------------------------
template <int MT, int MINW, bool OUT_F16, bool FUSE_VT>
__global__ __launch_bounds__(256, MINW)
void hgemm_lds(const _Float16* __restrict__ X, const _Float16* __restrict__ Wt,
               const float* __restrict__ bias, void* __restrict__ Cout,
               _Float16* __restrict__ vt, int M, int N, int K)
{
    constexpr int BM = MT * 32;
    constexpr int ACALLS = BM / 32;
    __shared__ _Float16 As[BM][64];
    __shared__ _Float16 Bs[128][64];

    const int tid  = threadIdx.x;
    const int wave = tid >> 6, lane = tid & 63;
    const int quad = lane >> 4, l15 = lane & 15;
    const int wm = (wave >> 1) * (MT * 16);
    const int wn = (wave & 1) * 64;
    const int m0 = blockIdx.y * BM, n0 = blockIdx.x * 128;

    const int srow = lane >> 3;
    const int scol = ((lane & 7) ^ srow) * 8;

    const _Float16* xg[ACALLS];
#pragma unroll
    for (int c = 0; c < ACALLS; ++c)
        xg[c] = X + (size_t)(m0 + wave * (BM / 4) + c * 8 + srow) * K + scol;
    const _Float16* wg[4];
#pragma unroll
    for (int c = 0; c < 4; ++c)
        wg[c] = Wt + (size_t)(n0 + wave * 32 + c * 8 + srow) * K + scol;

    f32x4 acc[MT][4] = {};
    const int sx = l15 & 7;

    for (int k0 = 0; k0 < K; k0 += 64) {
#pragma unroll
        for (int c = 0; c < ACALLS; ++c)
            stage16(xg[c] + k0, &As[wave * (BM / 4) + c * 8][0], lane);
#pragma unroll
        for (int c = 0; c < 4; ++c)
            stage16(wg[c] + k0, &Bs[wave * 32 + c * 8][0], lane);
        __syncthreads();

#pragma unroll
        for (int cc = 0; cc < 2; ++cc) {
            half8 af[MT], bf[4];
#pragma unroll
            for (int mt = 0; mt < MT; ++mt)
                af[mt] = *(const half8*)&As[wm + mt * 16 + l15][(((cc * 4 + quad) ^ sx)) * 8];
#pragma unroll
            for (int nt = 0; nt < 4; ++nt)
                bf[nt] = *(const half8*)&Bs[wn + nt * 16 + l15][(((cc * 4 + quad) ^ sx)) * 8];
#pragma unroll
            for (int mt = 0; mt < MT; ++mt)
#pragma unroll
                for (int nt = 0; nt < 4; ++nt)
                    acc[mt][nt] = __builtin_amdgcn_mfma_f32_16x16x32_f16(
                        af[mt], bf[nt], acc[mt][nt], 0, 0, 0);
        }
        __syncthreads();
    }

    if (FUSE_VT && n0 >= 2 * EMB) {
#pragma unroll
        for (int nt = 0; nt < 4; ++nt) {
            const int c  = n0 + wn + nt * 16 + l15;
            const float bv = bias[c];
            const int vcol = c - 2 * EMB;
            const int hh = vcol >> 6, dd = vcol & 63;
#pragma unroll
            for (int mt = 0; mt < MT; ++mt) {
                const int r = m0 + wm + mt * 16 + quad * 4;
                const int bb = r >> 11, ss = r & 2047;
                half4 o = { (_Float16)(acc[mt][nt][0] + bv), (_Float16)(acc[mt][nt][1] + bv),
                            (_Float16)(acc[mt][nt][2] + bv), (_Float16)(acc[mt][nt][3] + bv) };
                *(half4*)(vt + ((size_t)(bb * NH + hh) * HD + dd) * S_LEN + ss) = o;
            }
        }
        return;
    }

#pragma unroll
    for (int nt = 0; nt < 4; ++nt) {
        const int c = n0 + wn + nt * 16 + l15;
        const float bv = bias[c];
#pragma unroll
        for (int mt = 0; mt < MT; ++mt)
#pragma unroll
            for (int reg = 0; reg < 4; ++reg) {
                const int r = m0 + wm + mt * 16 + quad * 4 + reg;
                const float v = acc[mt][nt][reg] + bv;
                if (OUT_F16)
                    ((_Float16*)Cout)[(size_t)r * N + c] = (_Float16)v;
                else
                    ((float*)Cout)[(size_t)r * N + c] = v;
            }
    }
}

// ---------------------------------------------------------------------------
// MFMA flash attention v7: paired complementary q-tiles per block.
// Grid 512: xcd=n&7 (4 bh/XCD), j=n>>5 in 0..15 -> stream A qt=j, stream B
// qt=31-j. Uniform 17 k-tiles/block. K/V staged once, fragments shared by
// both streams; two independent softmax chains interleave in one BB.
// ---------------------------------------------------------------------------
__global__ __launch_bounds__(256, 2)
void attn_fa_mfma7(const _Float16* __restrict__ qkv,
                   const _Float16* __restrict__ vt,
                   _Float16* __restrict__ outh)
{
    __shared__ _Float16 Ks[128][64];
    __shared__ _Float16 Vs[64][128];

    const int n   = blockIdx.x;
    const int xcd = n & 7, g = (n >> 3) & 3, j = n >> 5;
    const int bh  = xcd * 4 + g;
    const int qta = j, qtb = 31 - j;
    const int b = bh >> 4, h = bh & 15;

    const int tid  = threadIdx.x;
    const int wave = tid >> 6, lane = tid & 63;
    const int quad = lane >> 4, l15 = lane & 15;
    const size_t row0 = (size_t)b * S_LEN;

    const _Float16 qscale = (_Float16)0.0901684400555602f;
    half8 qfa[2], qfb[2];
    {
        const _Float16* qpa = qkv + (row0 + qta * 64 + wave * 16 + l15) * QKV_N + h * HD + quad * 8;
        const _Float16* qpb = qkv + (row0 + qtb * 64 + wave * 16 + l15) * QKV_N + h * HD + quad * 8;
#pragma unroll
        for (int c = 0; c < 2; ++c) {
            half8 qa = *(const half8*)(qpa + c * 32);
            half8 qb = *(const half8*)(qpb + c * 32);
#pragma unroll
            for (int j2 = 0; j2 < 8; ++j2) { qa[j2] *= qscale; qb[j2] *= qscale; }
            qfa[c] = qa; qfb[c] = qb;
        }
    }

    f32x4 o_a[4] = {}, o_b[4] = {};
    float m_a = -1e30f, l_a = 0.0f, m_b = -1e30f, l_b = 0.0f;

    const int ksrow = lane >> 3;
    const int kscol = ((lane & 7) ^ ksrow) * 8;
    const int vsrow = lane >> 4;
    const _Float16* vbase = vt + (size_t)bh * HD * S_LEN;
    const int sxk = l15 & 7;

    // per-stream softmax + P pack (independent chains; inlined twice per tile)
    auto softmax_pack = [&](f32x4 (&st)[8], half4 (&pf)[8], float& m_i, float& l_i,
                            f32x4 (&o_acc)[4]) {
        float rm = fmaxf(fmaxf(st[0][0], st[0][1]), fmaxf(st[0][2], st[0][3]));
#pragma unroll
        for (int nt = 1; nt < 8; ++nt) {
            rm = fmaxf(rm, fmaxf(st[nt][0], st[nt][1]));
            rm = fmaxf(rm, fmaxf(st[nt][2], st[nt][3]));
        }
        rm = fmaxf(rm, __shfl_xor(rm, 16));
        rm = fmaxf(rm, __shfl_xor(rm, 32));
        const float mnew = fmaxf(m_i, rm);
        if (__ballot(mnew > m_i)) {
            const float alpha = __builtin_amdgcn_exp2f(m_i - mnew);
            l_i *= alpha;
#pragma unroll
            for (int dt = 0; dt < 4; ++dt)
#pragma unroll
                for (int reg = 0; reg < 4; ++reg) o_acc[dt][reg] *= alpha;
        }
        m_i = mnew;
        float rs = 0.0f;
#pragma unroll
        for (int nt = 0; nt < 8; ++nt) {
            float p0 = __builtin_amdgcn_exp2f(st[nt][0] - mnew);
            float p1 = __builtin_amdgcn_exp2f(st[nt][1] - mnew);
            float p2 = __builtin_amdgcn_exp2f(st[nt][2] - mnew);
            float p3 = __builtin_amdgcn_exp2f(st[nt][3] - mnew);
            rs += (p0 + p1) + (p2 + p3);
            pf[nt] = half4{ (_Float16)p0, (_Float16)p1, (_Float16)p2, (_Float16)p3 };
        }
        rs += __shfl_xor(rs, 16);
        rs += __shfl_xor(rs, 32);
        l_i += rs;
    };

    const int ktNa = (qta + 2) >> 1;
    const int ktNb = (qtb + 2) >> 1;     // = 17 - ktNa (pairs sum uniform)

    for (int kt = 0; kt < ktNb; ++kt) {
        __syncthreads();
        {
            const _Float16* kbase = qkv + (row0 + kt * 128) * QKV_N + EMB + h * HD;
#pragma unroll
            for (int c = 0; c < 4; ++c) {
                const int r0 = wave * 32 + c * 8;
                stage16(kbase + (size_t)(r0 + ksrow) * QKV_N + kscol, &Ks[r0][0], lane);
            }
#pragma unroll
            for (int c = 0; c < 4; ++c) {
                const int r0 = wave * 16 + c * 4;
                const int sgv = ((lane & 15) ^ (c * 4 + vsrow)) * 8;
                stage16(vbase + (size_t)(r0 + vsrow) * S_LEN + kt * 128 + sgv, &Vs[r0][0], lane);
            }
        }
        __syncthreads();

        if (kt < ktNa) {
            // ---- dual-stream tile: shared kf/vf, interleaved chains ----
            f32x4 sa[8] = {}, sb[8] = {};
#pragma unroll
            for (int c = 0; c < 2; ++c)
#pragma unroll
                for (int nt = 0; nt < 8; ++nt) {
                    half8 kf = *(const half8*)&Ks[nt * 16 + l15][((c * 4 + quad) ^ sxk) * 8];
                    sa[nt] = __builtin_amdgcn_mfma_f32_16x16x32_f16(kf, qfa[c], sa[nt], 0, 0, 0);
                    sb[nt] = __builtin_amdgcn_mfma_f32_16x16x32_f16(kf, qfb[c], sb[nt], 0, 0, 0);
                }
            if (kt == ktNa - 1) {          // mask stream A only (B is far from diag)
                const int q = qta * 64 + wave * 16 + l15;
#pragma unroll
                for (int nt = 0; nt < 8; ++nt) {
                    const int ks = kt * 128 + nt * 16 + quad * 4;
#pragma unroll
                    for (int reg = 0; reg < 4; ++reg)
                        if (ks + reg > q) sa[nt][reg] = -1e30f;
                }
            }
            half4 pfa[8], pfb[8];
            softmax_pack(sa, pfa, m_a, l_a, o_a);
            softmax_pack(sb, pfb, m_b, l_b, o_b);
#pragma unroll
            for (int nt = 0; nt < 8; ++nt)
#pragma unroll
                for (int dt = 0; dt < 4; ++dt) {
                    const int pg = ((2 * nt + (quad >> 1)) ^ l15) * 8 + (quad & 1) * 4;
                    half4 vf = *(const half4*)&Vs[dt * 16 + l15][pg];
                    o_a[dt] = __builtin_amdgcn_mfma_f32_16x16x16f16(vf, pfa[nt], o_a[dt], 0, 0, 0);
                    o_b[dt] = __builtin_amdgcn_mfma_f32_16x16x16f16(vf, pfb[nt], o_b[dt], 0, 0, 0);
                }
        } else {
            // ---- single-stream tile (B only) ----
            f32x4 sb[8] = {};
#pragma unroll
            for (int c = 0; c < 2; ++c)
#pragma unroll
                for (int nt = 0; nt < 8; ++nt) {
                    half8 kf = *(const half8*)&Ks[nt * 16 + l15][((c * 4 + quad) ^ sxk) * 8];
                    sb[nt] = __builtin_amdgcn_mfma_f32_16x16x32_f16(kf, qfb[c], sb[nt], 0, 0, 0);
                }
            if (kt == ktNb - 1) {
                const int q = qtb * 64 + wave * 16 + l15;
#pragma unroll
                for (int nt = 0; nt < 8; ++nt) {
                    const int ks = kt * 128 + nt * 16 + quad * 4;
#pragma unroll
                    for (int reg = 0; reg < 4; ++reg)
                        if (ks + reg > q) sb[nt][reg] = -1e30f;
                }
            }
            half4 pfb[8];
            softmax_pack(sb, pfb, m_b, l_b, o_b);
#pragma unroll
            for (int nt = 0; nt < 8; ++nt)
#pragma unroll
                for (int dt = 0; dt < 4; ++dt) {
                    const int pg = ((2 * nt + (quad >> 1)) ^ l15) * 8 + (quad & 1) * 4;
                    half4 vf = *(const half4*)&Vs[dt * 16 + l15][pg];
                    o_b[dt] = __builtin_amdgcn_mfma_f32_16x16x16f16(vf, pfb[nt], o_b[dt], 0, 0, 0);
                }
        }
    }

    // ---- epilogues ----
    {
        const float inv = 1.0f / l_a;
        const size_t r = row0 + qta * 64 + wave * 16 + l15;
#pragma unroll
        for (int dt = 0; dt < 4; ++dt) {
            half4 o = { (_Float16)(o_a[dt][0] * inv), (_Float16)(o_a[dt][1] * inv),
                        (_Float16)(o_a[dt][2] * inv), (_Float16)(o_a[dt][3] * inv) };
            *(half4*)(outh + r * EMB + h * HD + dt * 16 + quad * 4) = o;
        }
    }
    {
        const float inv = 1.0f / l_b;
        const size_t r = row0 + qtb * 64 + wave * 16 + l15;
#pragma unroll
        for (int dt = 0; dt < 4; ++dt) {
            half4 o = { (_Float16)(o_b[dt][0] * inv), (_Float16)(o_b[dt][1] * inv),
                        (_Float16)(o_b[dt][2] * inv), (_Float16)(o_b[dt][3] * inv) };
            *(half4*)(outh + r * EMB + h * HD + dt * 16 + quad * 4) = o;
        }
    }
}

// ---------------------------------------------------------------------------
extern "C" void kernel_launch(void* const* d_in, const int* in_sizes, int n_in,
                              void* d_out, int out_size, void* d_ws, size_t ws_size,
                              hipStream_t stream)
{
    const float* hidden = (const float*)d_in[0];
    const float* w_attn = (const float*)d_in[1];
    const float* b_attn = (const float*)d_in[2];
    const float* w_proj = (const float*)d_in[3];
    const float* b_proj = (const float*)d_in[4];

    _Float16* hidden_h = (_Float16*)d_ws;                        // 4M
    _Float16* wattn_t  = hidden_h + (size_t)MROWS * EMB;         // 3M
    _Float16* wproj_t  = wattn_t + (size_t)EMB * QKV_N;          // 1M
    _Float16* qkv_h    = wproj_t + (size_t)EMB * EMB;            // 12M
    _Float16* attn_h   = qkv_h + (size_t)MROWS * QKV_N;          // 4M
    _Float16* vt       = attn_h + (size_t)MROWS * EMB;           // 4M

    prep_all<<<8192, 256, 0, stream>>>(hidden, w_attn, w_proj,
                                       hidden_h, wattn_t, wproj_t);

    hgemm_lds<4, 3, true, true><<<dim3(QKV_N / 128, MROWS / 128), 256, 0, stream>>>(
        hidden_h, wattn_t, b_attn, qkv_h, vt, MROWS, QKV_N, EMB);

    attn_fa_mfma7<<<dim3(512), 256, 0, stream>>>(qkv_h, vt, attn_h);

    hgemm_lds<2, 4, false, false><<<dim3(EMB / 128, MROWS / 64), 256, 0, stream>>>(
        attn_h, wproj_t, b_proj, d_out, nullptr, MROWS, EMB, EMB);
}